// Round 8
// baseline (394.985 us; speedup 1.0000x reference)
//
#include <hip/hip_runtime.h>
#include <hip/hip_bf16.h>

typedef __attribute__((ext_vector_type(8))) short short8;
typedef __attribute__((ext_vector_type(4))) float f32x4;
typedef __attribute__((ext_vector_type(4))) unsigned short us4;

#define DIMC 768
#define HIDDENC 3072
#define NTOK 8192
#define SEQ 1024
#define NHEAD 12
#define HDIM 64

__device__ inline unsigned short f2bf(float f) {
  union { float f; unsigned u; } x; x.f = f;
  unsigned r = (x.u + 0x7FFFu + ((x.u >> 16) & 1u)) >> 16;
  return (unsigned short)r;
}

__device__ inline void gload_lds16(const void* g, void* lds) {
  __builtin_amdgcn_global_load_lds((const __attribute__((address_space(1))) unsigned*)g,
                                   (__attribute__((address_space(3))) unsigned*)lds, 16, 0, 0);
}

// ---------------- weight transpose + fp32->bf16 ----------------
// W: [K][N] f32  ->  Wt: [N][K] bf16
__global__ void wtrans(const float* __restrict__ W, unsigned short* __restrict__ Wt,
                       int K, int N) {
  __shared__ float tile[32][33];
  const int bx = blockIdx.x * 32;  // N
  const int by = blockIdx.y * 32;  // K
  const int tx = threadIdx.x, ty = threadIdx.y;
#pragma unroll
  for (int i = 0; i < 32; i += 8) tile[ty + i][tx] = W[(size_t)(by + ty + i) * N + bx + tx];
  __syncthreads();
#pragma unroll
  for (int i = 0; i < 32; i += 8)
    Wt[(size_t)(bx + ty + i) * K + by + tx] = f2bf(tile[tx][ty + i]);
}

// ---------------- V transpose: qkv V-part -> vT[b*768 + (h*64+d)][n] ----------------
__global__ void vtrans(const unsigned short* __restrict__ qkv, unsigned short* __restrict__ vT) {
  __shared__ unsigned short tile[32][33];
  const int bc = blockIdx.x * 32;  // c in [0,768)
  const int bn = blockIdx.y * 32;  // n in [0,1024)
  const int b = blockIdx.z;
  const int tx = threadIdx.x, ty = threadIdx.y;
#pragma unroll
  for (int i = 0; i < 32; i += 8)
    tile[ty + i][tx] = qkv[(size_t)(b * SEQ + bn + ty + i) * (3 * DIMC) + 2 * DIMC + bc + tx];
  __syncthreads();
#pragma unroll
  for (int i = 0; i < 32; i += 8)
    vT[(size_t)(b * DIMC + bc + ty + i) * SEQ + bn + tx] = tile[tx][ty + i];
}

// ---------------- LayerNorm over 768, f32 in -> bf16 out ----------------
__global__ __launch_bounds__(256) void ln_768(const float* __restrict__ x,
                                              const float* __restrict__ g,
                                              const float* __restrict__ b,
                                              unsigned short* __restrict__ out) {
  const int row = blockIdx.x;
  const int t = threadIdx.x;
  const float* xr = x + (size_t)row * DIMC;
  float v0 = xr[t], v1 = xr[t + 256], v2 = xr[t + 512];
  float s = v0 + v1 + v2;
  float ss = v0 * v0 + v1 * v1 + v2 * v2;
#pragma unroll
  for (int m = 1; m < 64; m <<= 1) { s += __shfl_xor(s, m); ss += __shfl_xor(ss, m); }
  __shared__ float red[8];
  const int w = t >> 6, l = t & 63;
  if (l == 0) { red[w] = s; red[4 + w] = ss; }
  __syncthreads();
  s = red[0] + red[1] + red[2] + red[3];
  ss = red[4] + red[5] + red[6] + red[7];
  const float mu = s * (1.0f / 768.0f);
  const float var = ss * (1.0f / 768.0f) - mu * mu;
  const float rstd = rsqrtf(var + 1e-5f);
  out[(size_t)row * DIMC + t]       = f2bf((v0 - mu) * rstd * g[t]       + b[t]);
  out[(size_t)row * DIMC + t + 256] = f2bf((v1 - mu) * rstd * g[t + 256] + b[t + 256]);
  out[(size_t)row * DIMC + t + 512] = f2bf((v2 - mu) * rstd * g[t + 512] + b[t + 512]);
}

// ---------------- GEMM v3: 2-phase dbuf + fragment-ordered (conflict-free) LDS ----------------
// C[M][N] = A[M][K] @ Bt[N][K]^T + bias (+res) (+gelu). BM=128, BN in {128,64}, BK=32,
// 4 waves (2x2), wave computes 64 x BN/2 via 4 x NJ 16x16x32 MFMA frags.
// LDS layout is FRAGMENT-ORDERED: slot s (16B) holds row=(s>>6)*16+(s&15), kcols=((s>>4)&3)*8..+7.
// Staging: linear LDS dest (global_load_lds requirement), pre-swizzled per-lane global source.
// Fragment read: block b -> byte b*1024 + lane*16 (64 lanes x consecutive 16B = conflict-free).
// XCD-aware block swizzle (nwg % 8 == 0 for all our grids).
template <int BN, int GELU, int RES, int OUT_BF16>
__global__ __launch_bounds__(256) void gemm_bt(const unsigned short* __restrict__ A,
                                               const unsigned short* __restrict__ Bt,
                                               const float* __restrict__ bias,
                                               const float* __restrict__ res,
                                               float* __restrict__ Cf,
                                               unsigned short* __restrict__ Cb,
                                               int M, int N, int K) {
  constexpr int NJ = BN / 32;   // N-frags per wave (BN=128 -> 4, BN=64 -> 2)
  __shared__ __align__(16) unsigned short As[2][128 * 32];
  __shared__ __align__(16) unsigned short Bs[2][BN * 32];
  const int gx = gridDim.x;
  const int nwg = gx * gridDim.y;
  const int orig = blockIdx.y * gx + blockIdx.x;
  const int cpx = nwg >> 3;                       // nwg % 8 == 0
  const int wg = (orig & 7) * cpx + (orig >> 3);
  const int bxx = wg % gx, byy = wg / gx;
  const int t = threadIdx.x;
  const int w = t >> 6, l = t & 63;
  const int lr = l & 15, lg = l >> 4;
  const int wr = w >> 1, wc = w & 1;
  const unsigned short* Ag = A + (size_t)byy * 128 * K;
  const unsigned short* Bg = Bt + (size_t)bxx * BN * K;
  // slot s = t stages row (s>>6)*16 + (s&15), kchunk (s>>4)&3; slot t+256 = +64 rows
  const size_t a1 = (size_t)((t >> 6) * 16 + (t & 15)) * K + (size_t)((t >> 4) & 3) * 8;
  const size_t a2 = a1 + (size_t)64 * K;
  f32x4 acc[4][NJ] = {};

  auto stage = [&](int buf, int k0) {
    gload_lds16(Ag + a1 + k0, &As[buf][w * 512]);
    gload_lds16(Ag + a2 + k0, &As[buf][2048 + w * 512]);
    gload_lds16(Bg + a1 + k0, &Bs[buf][w * 512]);
    if (BN == 128) gload_lds16(Bg + a2 + k0, &Bs[buf][2048 + w * 512]);
  };
  auto compute = [&](int buf) {
    short8 af[4], bf[NJ];
#pragma unroll
    for (int i = 0; i < 4; i++)
      af[i] = *(const short8*)((const char*)&As[buf][0] + (wr * 4 + i) * 1024 + l * 16);
#pragma unroll
    for (int j = 0; j < NJ; j++)
      bf[j] = *(const short8*)((const char*)&Bs[buf][0] + (wc * NJ + j) * 1024 + l * 16);
#pragma unroll
    for (int i = 0; i < 4; i++)
#pragma unroll
      for (int j = 0; j < NJ; j++)
        acc[i][j] = __builtin_amdgcn_mfma_f32_16x16x32_bf16(af[i], bf[j], acc[i][j], 0, 0, 0);
  };

  const int nt = K >> 5;  // even for all our K (768->24, 3072->96)
  stage(0, 0);
  __syncthreads();
  for (int tt = 0; tt < nt; tt += 2) {
    stage(1, (tt + 1) << 5);    // prefetch tile tt+1 (always valid: nt even)
    compute(0);
    __syncthreads();            // drains prefetch (overlapped with compute) + read fence
    if (tt + 2 < nt) stage(0, (tt + 2) << 5);
    compute(1);
    __syncthreads();
  }

  const int rbase = byy * 128 + wr * 64;
  const int cbase = bxx * BN + wc * (16 * NJ);
#pragma unroll
  for (int i = 0; i < 4; i++)
#pragma unroll
    for (int j = 0; j < NJ; j++) {
      const int c = cbase + j * 16 + lr;
      const float bz = bias[c];
#pragma unroll
      for (int v = 0; v < 4; v++) {
        const int r = rbase + i * 16 + lg * 4 + v;
        float val = acc[i][j][v] + bz;
        if (RES) val += res[(size_t)r * N + c];
        if (GELU) {
          // gelu(u) ~= u * sigmoid(1.595769f*(u + 0.044715f*u^3)); inf-safe.
          const float u = val;
          const float c2u = u * (1.5957691216f + 0.0713548162f * u * u);
          val = u - u * __builtin_amdgcn_rcpf(__expf(c2u) + 1.0f);
        }
        if (OUT_BF16) Cb[(size_t)r * N + c] = f2bf(val);
        else          Cf[(size_t)r * N + c] = val;
      }
    }
}

// ---------------- fused attention (v5: swapped QK^T + T14 async K/V reg-prefetch) ----
// qkv bf16 [8192][2304]; vT bf16 [8*768][1024]; o bf16 [8192][768]
// grid (16 qtiles, 12 heads, 8 batch), 256 threads (4 waves, 16 q-rows each)
// LDS tiles [row][64] bf16, byte-XOR swizzle: byte_in_row ^= (row&7)<<4.
__global__ __launch_bounds__(256) void attn(const unsigned short* __restrict__ qkv,
                                            const unsigned short* __restrict__ vT,
                                            unsigned short* __restrict__ o) {
  const int qt = blockIdx.x, h = blockIdx.y, b = blockIdx.z;
  const int t = threadIdx.x, w = t >> 6, l = t & 63;
  const int lr = l & 15, lg = l >> 4;
  const int ld = 3 * DIMC;
  __shared__ __align__(16) unsigned short Ks[64 * 64];
  __shared__ __align__(16) unsigned short Vt[64 * 64];
  __shared__ __align__(16) unsigned short Ps[4][16 * 64];

  const unsigned short* qb = qkv + (size_t)(b * SEQ + qt * 64 + w * 16) * ld + h * HDIM;
  short8 qf0 = *(const short8*)(qb + (size_t)lr * ld + lg * 8);        // Q rows q=lr (B-operand)
  short8 qf1 = *(const short8*)(qb + (size_t)lr * ld + 32 + lg * 8);

  const int r = t >> 2, c4 = (t & 3) * 16;
  const int sw = (r & 7) << 4;
  const unsigned short* kb_base = qkv + (size_t)(b * SEQ) * ld + DIMC + h * HDIM + (size_t)r * ld;
  const unsigned short* vrow = vT + (size_t)(b * DIMC + h * HDIM + r) * SEQ;

  // staging regs for current tile (kt=0)
  short8 ck0 = *(const short8*)(kb_base + c4);
  short8 ck1 = *(const short8*)(kb_base + c4 + 8);
  short8 cv0 = *(const short8*)(vrow + c4);
  short8 cv1 = *(const short8*)(vrow + c4 + 8);

  float m_run = -1e30f, l_run = 0.f;   // stats for q = w*16 + lr (replicated over lg)
  f32x4 oacc[4];                       // O[q=lg*4+v][d=dn*16+lr]
#pragma unroll
  for (int i = 0; i < 4; i++) oacc[i] = (f32x4){0.f, 0.f, 0.f, 0.f};

  for (int kt = 0; kt < 16; ++kt) {
    // ---- write current K/V tile to LDS (swizzled) ----
    {
      char* ksb = (char*)Ks + r * 128;
      *(short8*)(ksb + ((c4 * 2) ^ sw))      = ck0;
      *(short8*)(ksb + ((c4 * 2 + 16) ^ sw)) = ck1;
      char* vsb = (char*)Vt + r * 128;
      *(short8*)(vsb + ((c4 * 2) ^ sw))      = cv0;
      *(short8*)(vsb + ((c4 * 2 + 16) ^ sw)) = cv1;
    }
    // ---- prefetch next tile into regs (clamped; last iter wasted but valid) ----
    const int nk = (kt + 1) & 15;
    short8 nk0 = *(const short8*)(kb_base + (size_t)nk * 64 * ld + c4);
    short8 nk1 = *(const short8*)(kb_base + (size_t)nk * 64 * ld + c4 + 8);
    short8 nv0 = *(const short8*)(vrow + nk * 64 + c4);
    short8 nv1 = *(const short8*)(vrow + nk * 64 + c4 + 8);

    asm volatile("s_waitcnt lgkmcnt(0)" ::: "memory");  // K/V ds_writes visible
    __builtin_amdgcn_s_barrier();
    __builtin_amdgcn_sched_barrier(0);

    // ---- swapped QK^T: sf[n][v] = S[q=lr][k=n*16+lg*4+v] ----
    f32x4 sf[4];
#pragma unroll
    for (int n = 0; n < 4; n++) sf[n] = (f32x4){0.f, 0.f, 0.f, 0.f};
#pragma unroll
    for (int kc = 0; kc < 2; kc++) {
      short8 q = kc ? qf1 : qf0;
#pragma unroll
      for (int n = 0; n < 4; n++) {
        const int row = n * 16 + lr;
        short8 kf = *(const short8*)((const char*)Ks + row * 128 +
                                     (((kc * 32 + lg * 8) * 2) ^ ((row & 7) << 4)));
        sf[n] = __builtin_amdgcn_mfma_f32_16x16x32_bf16(kf, q, sf[n], 0, 0, 0);
      }
    }

    // ---- online softmax, q = lr local ----
    float pv[4][4];
    float tmax = -1e30f;
#pragma unroll
    for (int n = 0; n < 4; n++)
#pragma unroll
      for (int v = 0; v < 4; v++) {
        float s = sf[n][v] * 0.125f;
        s = fminf(fmaxf(s, -50.f), 50.f);
        pv[n][v] = s;
        tmax = fmaxf(tmax, s);
      }
    tmax = fmaxf(tmax, __shfl_xor(tmax, 16));
    tmax = fmaxf(tmax, __shfl_xor(tmax, 32));
    const float mn = fmaxf(m_run, tmax);
    const float alpha = __expf(m_run - mn);
    m_run = mn;
    l_run *= alpha;
    float psum = 0.f;
    char* psw = (char*)&Ps[w][0] + lr * 128;
    const int psx = (lr & 7) << 4;
#pragma unroll
    for (int n = 0; n < 4; n++) {
      us4 pk;
#pragma unroll
      for (int v = 0; v < 4; v++) {
        float e = __expf(pv[n][v] - mn);
        psum += e;
        pk[v] = f2bf(e);
      }
      *(us4*)(psw + ((n * 32 + lg * 8) ^ psx)) = pk;   // P[q=lr][k=n*16+lg*4 ..+3]
    }
    psum += __shfl_xor(psum, 16);
    psum += __shfl_xor(psum, 32);
    l_run += psum;

    // rescale oacc rows q=lg*4+v with that q's alpha (broadcast from lane lr==q)
#pragma unroll
    for (int v = 0; v < 4; v++) {
      const float av = __shfl(alpha, lg * 4 + v);
#pragma unroll
      for (int dn = 0; dn < 4; dn++) oacc[dn][v] *= av;
    }

    // drain wave-local Ps writes before reading them (no block barrier needed)
    asm volatile("s_waitcnt lgkmcnt(0)" ::: "memory");
    __builtin_amdgcn_sched_barrier(0);

    // ---- PV: A = P[q=lr][k-frag], B = Vt[d=dn*16+lr][k-frag] (swizzled reads) ----
#pragma unroll
    for (int kc = 0; kc < 2; kc++) {
      short8 pf = *(const short8*)((const char*)&Ps[w][0] + lr * 128 +
                                   (((kc * 32 + lg * 8) * 2) ^ ((lr & 7) << 4)));
#pragma unroll
      for (int dn = 0; dn < 4; dn++) {
        const int row = dn * 16 + lr;
        short8 vf = *(const short8*)((const char*)Vt + row * 128 +
                                     (((kc * 32 + lg * 8) * 2) ^ ((row & 7) << 4)));
        oacc[dn] = __builtin_amdgcn_mfma_f32_16x16x32_bf16(pf, vf, oacc[dn], 0, 0, 0);
      }
    }
    __builtin_amdgcn_sched_barrier(0);
    __builtin_amdgcn_s_barrier();   // all waves done reading Ks/Vt before next overwrite
    ck0 = nk0; ck1 = nk1; cv0 = nv0; cv1 = nv1;
  }

  unsigned short* ob = o + (size_t)(b * SEQ + qt * 64 + w * 16) * DIMC + h * HDIM;
#pragma unroll
  for (int v = 0; v < 4; v++) {
    const float lv = __shfl(l_run, lg * 4 + v);
    const float inv = 1.0f / lv;
#pragma unroll
    for (int dn = 0; dn < 4; dn++)
      ob[(size_t)(lg * 4 + v) * DIMC + dn * 16 + lr] = f2bf(oacc[dn][v] * inv);
  }
}

extern "C" void kernel_launch(void* const* d_in, const int* in_sizes, int n_in,
                              void* d_out, int out_size, void* d_ws, size_t ws_size,
                              hipStream_t stream) {
  const float* x      = (const float*)d_in[0];
  const float* ln1_g  = (const float*)d_in[1];
  const float* ln1_b  = (const float*)d_in[2];
  const float* w_qkv  = (const float*)d_in[3];
  const float* b_qkv  = (const float*)d_in[4];
  const float* w_proj = (const float*)d_in[5];
  const float* b_proj = (const float*)d_in[6];
  const float* ln2_g  = (const float*)d_in[7];
  const float* ln2_b  = (const float*)d_in[8];
  const float* w_fc1  = (const float*)d_in[9];
  const float* b_fc1  = (const float*)d_in[10];
  const float* w_fc2  = (const float*)d_in[11];
  const float* b_fc2  = (const float*)d_in[12];
  float* out = (float*)d_out;

  char* p = (char*)d_ws;
  unsigned short* wqkvT  = (unsigned short*)p; p += (size_t)2304 * 768 * 2;
  unsigned short* wprojT = (unsigned short*)p; p += (size_t)768 * 768 * 2;
  unsigned short* wfc1T  = (unsigned short*)p; p += (size_t)3072 * 768 * 2;
  unsigned short* wfc2T  = (unsigned short*)p; p += (size_t)768 * 3072 * 2;
  unsigned short* h1     = (unsigned short*)p; p += (size_t)NTOK * 768 * 2;
  float*          x1     = (float*)p;          p += (size_t)NTOK * 768 * 4;
  unsigned short* qkv    = (unsigned short*)p; p += (size_t)NTOK * 2304 * 2;
  unsigned short* ob     = (unsigned short*)p; p += (size_t)NTOK * 768 * 2;
  unsigned short* g      = qkv;            // alias: qkv region, dead by FC1
  unsigned short* vT     = (unsigned short*)x1;  // alias: x1 dead until proj GEMM; vT dead after attn

  dim3 tb(32, 8);
  wtrans<<<dim3(2304 / 32, 768 / 32), tb, 0, stream>>>(w_qkv, wqkvT, 768, 2304);
  wtrans<<<dim3(768 / 32, 768 / 32), tb, 0, stream>>>(w_proj, wprojT, 768, 768);
  wtrans<<<dim3(3072 / 32, 768 / 32), tb, 0, stream>>>(w_fc1, wfc1T, 768, 3072);
  wtrans<<<dim3(768 / 32, 3072 / 32), tb, 0, stream>>>(w_fc2, wfc2T, 3072, 768);

  ln_768<<<NTOK, 256, 0, stream>>>(x, ln1_g, ln1_b, h1);
  gemm_bt<128, 0, 0, 1><<<dim3(18, 64), 256, 0, stream>>>(h1, wqkvT, b_qkv, nullptr, nullptr,
                                                          qkv, NTOK, 2304, 768);
  vtrans<<<dim3(24, 32, 8), tb, 0, stream>>>(qkv, vT);
  attn<<<dim3(16, 12, 8), 256, 0, stream>>>(qkv, vT, ob);
  gemm_bt<64, 0, 1, 0><<<dim3(12, 64), 256, 0, stream>>>(ob, wprojT, b_proj, x, x1, nullptr,
                                                         NTOK, 768, 768);
  ln_768<<<NTOK, 256, 0, stream>>>(x1, ln2_g, ln2_b, h1);
  gemm_bt<128, 1, 0, 1><<<dim3(24, 64), 256, 0, stream>>>(h1, wfc1T, b_fc1, nullptr, nullptr,
                                                          g, NTOK, 3072, 768);
  gemm_bt<64, 0, 1, 0><<<dim3(12, 64), 256, 0, stream>>>(g, wfc2T, b_fc2, x1, out, nullptr,
                                                         NTOK, 768, 3072);
}

// Round 9
// 313.951 us; speedup vs baseline: 1.2581x; 1.2581x over previous
//
#include <hip/hip_runtime.h>
#include <hip/hip_bf16.h>

typedef __attribute__((ext_vector_type(8))) short short8;
typedef __attribute__((ext_vector_type(4))) float f32x4;
typedef __attribute__((ext_vector_type(4))) unsigned short us4;

#define DIMC 768
#define HIDDENC 3072
#define NTOK 8192
#define SEQ 1024
#define NHEAD 12
#define HDIM 64

__device__ inline unsigned short f2bf(float f) {
  union { float f; unsigned u; } x; x.f = f;
  unsigned r = (x.u + 0x7FFFu + ((x.u >> 16) & 1u)) >> 16;
  return (unsigned short)r;
}

__device__ inline void gload_lds16(const void* g, void* lds) {
  __builtin_amdgcn_global_load_lds((const __attribute__((address_space(1))) unsigned*)g,
                                   (__attribute__((address_space(3))) unsigned*)lds, 16, 0, 0);
}

// ---------------- weight transpose + fp32->bf16 ----------------
// W: [K][N] f32  ->  Wt: [N][K] bf16
__global__ void wtrans(const float* __restrict__ W, unsigned short* __restrict__ Wt,
                       int K, int N) {
  __shared__ float tile[32][33];
  const int bx = blockIdx.x * 32;  // N
  const int by = blockIdx.y * 32;  // K
  const int tx = threadIdx.x, ty = threadIdx.y;
#pragma unroll
  for (int i = 0; i < 32; i += 8) tile[ty + i][tx] = W[(size_t)(by + ty + i) * N + bx + tx];
  __syncthreads();
#pragma unroll
  for (int i = 0; i < 32; i += 8)
    Wt[(size_t)(bx + ty + i) * K + by + tx] = f2bf(tile[tx][ty + i]);
}

// ---------------- V transpose: qkv V-part -> vT[b*768 + (h*64+d)][n] ----------------
__global__ void vtrans(const unsigned short* __restrict__ qkv, unsigned short* __restrict__ vT) {
  __shared__ unsigned short tile[32][33];
  const int bc = blockIdx.x * 32;  // c in [0,768)
  const int bn = blockIdx.y * 32;  // n in [0,1024)
  const int b = blockIdx.z;
  const int tx = threadIdx.x, ty = threadIdx.y;
#pragma unroll
  for (int i = 0; i < 32; i += 8)
    tile[ty + i][tx] = qkv[(size_t)(b * SEQ + bn + ty + i) * (3 * DIMC) + 2 * DIMC + bc + tx];
  __syncthreads();
#pragma unroll
  for (int i = 0; i < 32; i += 8)
    vT[(size_t)(b * DIMC + bc + ty + i) * SEQ + bn + tx] = tile[tx][ty + i];
}

// ---------------- LayerNorm over 768, f32 in -> bf16 out ----------------
__global__ __launch_bounds__(256) void ln_768(const float* __restrict__ x,
                                              const float* __restrict__ g,
                                              const float* __restrict__ b,
                                              unsigned short* __restrict__ out) {
  const int row = blockIdx.x;
  const int t = threadIdx.x;
  const float* xr = x + (size_t)row * DIMC;
  float v0 = xr[t], v1 = xr[t + 256], v2 = xr[t + 512];
  float s = v0 + v1 + v2;
  float ss = v0 * v0 + v1 * v1 + v2 * v2;
#pragma unroll
  for (int m = 1; m < 64; m <<= 1) { s += __shfl_xor(s, m); ss += __shfl_xor(ss, m); }
  __shared__ float red[8];
  const int w = t >> 6, l = t & 63;
  if (l == 0) { red[w] = s; red[4 + w] = ss; }
  __syncthreads();
  s = red[0] + red[1] + red[2] + red[3];
  ss = red[4] + red[5] + red[6] + red[7];
  const float mu = s * (1.0f / 768.0f);
  const float var = ss * (1.0f / 768.0f) - mu * mu;
  const float rstd = rsqrtf(var + 1e-5f);
  out[(size_t)row * DIMC + t]       = f2bf((v0 - mu) * rstd * g[t]       + b[t]);
  out[(size_t)row * DIMC + t + 256] = f2bf((v1 - mu) * rstd * g[t + 256] + b[t + 256]);
  out[(size_t)row * DIMC + t + 512] = f2bf((v2 - mu) * rstd * g[t + 512] + b[t + 512]);
}

// ---------------- GEMM v4: 2-phase dbuf + XOR-slot LDS (coalesced AND conflict-free) -------
// C[M][N] = A[M][K] @ Bt[N][K]^T + bias (+res) (+gelu). BM=128, BN in {128,64}, BK=32,
// 4 waves (2x2), wave computes 64 x (BN/2) via 4 x NJ 16x16x32 MFMA frags.
// LDS 16B-slot map: slot s <-> (row = s>>2, kc = (s&3) ^ ((s>>3)&3)).
//  - staging (linear lds dest, slot = lane): lanes 4r..4r+3 read the SAME 64B global line
//    (kc permuted within the line) -> full coalescing.
//  - fragment read: byte = row*64 + (lg ^ ((lr>>1)&3))*16 -> each 16B unit of every 128B
//    bank window hit by exactly 2 lanes -> conflict-free (2-way is free).
// XCD-aware block swizzle (nwg % 8 == 0 for all our grids).
template <int BN, int GELU, int RES, int OUT_BF16>
__global__ __launch_bounds__(256) void gemm_bt(const unsigned short* __restrict__ A,
                                               const unsigned short* __restrict__ Bt,
                                               const float* __restrict__ bias,
                                               const float* __restrict__ res,
                                               float* __restrict__ Cf,
                                               unsigned short* __restrict__ Cb,
                                               int M, int N, int K) {
  constexpr int NJ = BN / 32;   // N-frags per wave (BN=128 -> 4, BN=64 -> 2)
  __shared__ __align__(16) unsigned short As[2][128 * 32];
  __shared__ __align__(16) unsigned short Bs[2][BN * 32];
  const int gx = gridDim.x;
  const int nwg = gx * gridDim.y;
  const int orig = blockIdx.y * gx + blockIdx.x;
  const int cpx = nwg >> 3;                       // nwg % 8 == 0
  const int wg = (orig & 7) * cpx + (orig >> 3);
  const int bxx = wg % gx, byy = wg / gx;
  const int t = threadIdx.x;
  const int w = t >> 6, l = t & 63;
  const int lr = l & 15, lg = l >> 4;
  const int wr = w >> 1, wc = w & 1;
  const unsigned short* Ag = A + (size_t)byy * 128 * K;
  const unsigned short* Bg = Bt + (size_t)bxx * BN * K;
  // stage source for slot s=t: row=s>>2, kc=(s&3)^((s>>3)&3); slot t+256 = +64 rows, same kc
  const int kc1 = (t & 3) ^ ((t >> 3) & 3);
  const size_t a1 = (size_t)(t >> 2) * K + (size_t)kc1 * 8;
  const size_t a2 = a1 + (size_t)64 * K;
  // fragment-read column offset (bytes within a row's 64B)
  const int fx = (lg ^ ((lr >> 1) & 3)) * 16;
  f32x4 acc[4][NJ] = {};

  auto stage = [&](int buf, int k0) {
    gload_lds16(Ag + a1 + k0, &As[buf][w * 512]);
    gload_lds16(Ag + a2 + k0, &As[buf][2048 + w * 512]);
    gload_lds16(Bg + a1 + k0, &Bs[buf][w * 512]);
    if (BN == 128) gload_lds16(Bg + a2 + k0, &Bs[buf][2048 + w * 512]);
  };
  auto compute = [&](int buf) {
    short8 af[4], bf[NJ];
#pragma unroll
    for (int i = 0; i < 4; i++)
      af[i] = *(const short8*)((const char*)&As[buf][0] +
                               (size_t)(wr * 64 + i * 16 + lr) * 64 + fx);
#pragma unroll
    for (int j = 0; j < NJ; j++)
      bf[j] = *(const short8*)((const char*)&Bs[buf][0] +
                               (size_t)(wc * (16 * NJ) + j * 16 + lr) * 64 + fx);
#pragma unroll
    for (int i = 0; i < 4; i++)
#pragma unroll
      for (int j = 0; j < NJ; j++)
        acc[i][j] = __builtin_amdgcn_mfma_f32_16x16x32_bf16(af[i], bf[j], acc[i][j], 0, 0, 0);
  };

  const int nt = K >> 5;  // even for all our K (768->24, 3072->96)
  stage(0, 0);
  __syncthreads();
  for (int tt = 0; tt < nt; tt += 2) {
    stage(1, (tt + 1) << 5);    // prefetch tile tt+1 (always valid: nt even)
    compute(0);
    __syncthreads();            // drains prefetch (overlapped with compute) + read fence
    if (tt + 2 < nt) stage(0, (tt + 2) << 5);
    compute(1);
    __syncthreads();
  }

  const int rbase = byy * 128 + wr * 64;
  const int cbase = bxx * BN + wc * (16 * NJ);
#pragma unroll
  for (int i = 0; i < 4; i++)
#pragma unroll
    for (int j = 0; j < NJ; j++) {
      const int c = cbase + j * 16 + lr;
      const float bz = bias[c];
#pragma unroll
      for (int v = 0; v < 4; v++) {
        const int r = rbase + i * 16 + lg * 4 + v;
        float val = acc[i][j][v] + bz;
        if (RES) val += res[(size_t)r * N + c];
        if (GELU) {
          // gelu(u) ~= u * sigmoid(1.595769f*(u + 0.044715f*u^3)); inf-safe.
          const float u = val;
          const float c2u = u * (1.5957691216f + 0.0713548162f * u * u);
          val = u - u * __builtin_amdgcn_rcpf(__expf(c2u) + 1.0f);
        }
        if (OUT_BF16) Cb[(size_t)r * N + c] = f2bf(val);
        else          Cf[(size_t)r * N + c] = val;
      }
    }
}

// ---------------- fused attention (v5: swapped QK^T + T14 async K/V reg-prefetch) ----
// qkv bf16 [8192][2304]; vT bf16 [8*768][1024]; o bf16 [8192][768]
// grid (16 qtiles, 12 heads, 8 batch), 256 threads (4 waves, 16 q-rows each)
// LDS tiles [row][64] bf16, byte-XOR swizzle: byte_in_row ^= (row&7)<<4.
__global__ __launch_bounds__(256) void attn(const unsigned short* __restrict__ qkv,
                                            const unsigned short* __restrict__ vT,
                                            unsigned short* __restrict__ o) {
  const int qt = blockIdx.x, h = blockIdx.y, b = blockIdx.z;
  const int t = threadIdx.x, w = t >> 6, l = t & 63;
  const int lr = l & 15, lg = l >> 4;
  const int ld = 3 * DIMC;
  __shared__ __align__(16) unsigned short Ks[64 * 64];
  __shared__ __align__(16) unsigned short Vt[64 * 64];
  __shared__ __align__(16) unsigned short Ps[4][16 * 64];

  const unsigned short* qb = qkv + (size_t)(b * SEQ + qt * 64 + w * 16) * ld + h * HDIM;
  short8 qf0 = *(const short8*)(qb + (size_t)lr * ld + lg * 8);        // Q rows q=lr (B-operand)
  short8 qf1 = *(const short8*)(qb + (size_t)lr * ld + 32 + lg * 8);

  const int r = t >> 2, c4 = (t & 3) * 16;
  const int sw = (r & 7) << 4;
  const unsigned short* kb_base = qkv + (size_t)(b * SEQ) * ld + DIMC + h * HDIM + (size_t)r * ld;
  const unsigned short* vrow = vT + (size_t)(b * DIMC + h * HDIM + r) * SEQ;

  // staging regs for current tile (kt=0)
  short8 ck0 = *(const short8*)(kb_base + c4);
  short8 ck1 = *(const short8*)(kb_base + c4 + 8);
  short8 cv0 = *(const short8*)(vrow + c4);
  short8 cv1 = *(const short8*)(vrow + c4 + 8);

  float m_run = -1e30f, l_run = 0.f;   // stats for q = w*16 + lr (replicated over lg)
  f32x4 oacc[4];                       // O[q=lg*4+v][d=dn*16+lr]
#pragma unroll
  for (int i = 0; i < 4; i++) oacc[i] = (f32x4){0.f, 0.f, 0.f, 0.f};

  for (int kt = 0; kt < 16; ++kt) {
    // ---- write current K/V tile to LDS (swizzled) ----
    {
      char* ksb = (char*)Ks + r * 128;
      *(short8*)(ksb + ((c4 * 2) ^ sw))      = ck0;
      *(short8*)(ksb + ((c4 * 2 + 16) ^ sw)) = ck1;
      char* vsb = (char*)Vt + r * 128;
      *(short8*)(vsb + ((c4 * 2) ^ sw))      = cv0;
      *(short8*)(vsb + ((c4 * 2 + 16) ^ sw)) = cv1;
    }
    // ---- prefetch next tile into regs (clamped; last iter wasted but valid) ----
    const int nk = (kt + 1) & 15;
    short8 nk0 = *(const short8*)(kb_base + (size_t)nk * 64 * ld + c4);
    short8 nk1 = *(const short8*)(kb_base + (size_t)nk * 64 * ld + c4 + 8);
    short8 nv0 = *(const short8*)(vrow + nk * 64 + c4);
    short8 nv1 = *(const short8*)(vrow + nk * 64 + c4 + 8);

    asm volatile("s_waitcnt lgkmcnt(0)" ::: "memory");  // K/V ds_writes visible
    __builtin_amdgcn_s_barrier();
    __builtin_amdgcn_sched_barrier(0);

    // ---- swapped QK^T: sf[n][v] = S[q=lr][k=n*16+lg*4+v] ----
    f32x4 sf[4];
#pragma unroll
    for (int n = 0; n < 4; n++) sf[n] = (f32x4){0.f, 0.f, 0.f, 0.f};
#pragma unroll
    for (int kc = 0; kc < 2; kc++) {
      short8 q = kc ? qf1 : qf0;
#pragma unroll
      for (int n = 0; n < 4; n++) {
        const int row = n * 16 + lr;
        short8 kf = *(const short8*)((const char*)Ks + row * 128 +
                                     (((kc * 32 + lg * 8) * 2) ^ ((row & 7) << 4)));
        sf[n] = __builtin_amdgcn_mfma_f32_16x16x32_bf16(kf, q, sf[n], 0, 0, 0);
      }
    }

    // ---- online softmax, q = lr local ----
    float pv[4][4];
    float tmax = -1e30f;
#pragma unroll
    for (int n = 0; n < 4; n++)
#pragma unroll
      for (int v = 0; v < 4; v++) {
        float s = sf[n][v] * 0.125f;
        s = fminf(fmaxf(s, -50.f), 50.f);
        pv[n][v] = s;
        tmax = fmaxf(tmax, s);
      }
    tmax = fmaxf(tmax, __shfl_xor(tmax, 16));
    tmax = fmaxf(tmax, __shfl_xor(tmax, 32));
    const float mn = fmaxf(m_run, tmax);
    const float alpha = __expf(m_run - mn);
    m_run = mn;
    l_run *= alpha;
    float psum = 0.f;
    char* psw = (char*)&Ps[w][0] + lr * 128;
    const int psx = (lr & 7) << 4;
#pragma unroll
    for (int n = 0; n < 4; n++) {
      us4 pk;
#pragma unroll
      for (int v = 0; v < 4; v++) {
        float e = __expf(pv[n][v] - mn);
        psum += e;
        pk[v] = f2bf(e);
      }
      *(us4*)(psw + ((n * 32 + lg * 8) ^ psx)) = pk;   // P[q=lr][k=n*16+lg*4 ..+3]
    }
    psum += __shfl_xor(psum, 16);
    psum += __shfl_xor(psum, 32);
    l_run += psum;

    // rescale oacc rows q=lg*4+v with that q's alpha (broadcast from lane lr==q)
#pragma unroll
    for (int v = 0; v < 4; v++) {
      const float av = __shfl(alpha, lg * 4 + v);
#pragma unroll
      for (int dn = 0; dn < 4; dn++) oacc[dn][v] *= av;
    }

    // drain wave-local Ps writes before reading them (no block barrier needed)
    asm volatile("s_waitcnt lgkmcnt(0)" ::: "memory");
    __builtin_amdgcn_sched_barrier(0);

    // ---- PV: A = P[q=lr][k-frag], B = Vt[d=dn*16+lr][k-frag] (swizzled reads) ----
#pragma unroll
    for (int kc = 0; kc < 2; kc++) {
      short8 pf = *(const short8*)((const char*)&Ps[w][0] + lr * 128 +
                                   (((kc * 32 + lg * 8) * 2) ^ ((lr & 7) << 4)));
#pragma unroll
      for (int dn = 0; dn < 4; dn++) {
        const int row = dn * 16 + lr;
        short8 vf = *(const short8*)((const char*)Vt + row * 128 +
                                     (((kc * 32 + lg * 8) * 2) ^ ((row & 7) << 4)));
        oacc[dn] = __builtin_amdgcn_mfma_f32_16x16x32_bf16(pf, vf, oacc[dn], 0, 0, 0);
      }
    }
    __builtin_amdgcn_sched_barrier(0);
    __builtin_amdgcn_s_barrier();   // all waves done reading Ks/Vt before next overwrite
    ck0 = nk0; ck1 = nk1; cv0 = nv0; cv1 = nv1;
  }

  unsigned short* ob = o + (size_t)(b * SEQ + qt * 64 + w * 16) * DIMC + h * HDIM;
#pragma unroll
  for (int v = 0; v < 4; v++) {
    const float lv = __shfl(l_run, lg * 4 + v);
    const float inv = 1.0f / lv;
#pragma unroll
    for (int dn = 0; dn < 4; dn++)
      ob[(size_t)(lg * 4 + v) * DIMC + dn * 16 + lr] = f2bf(oacc[dn][v] * inv);
  }
}

extern "C" void kernel_launch(void* const* d_in, const int* in_sizes, int n_in,
                              void* d_out, int out_size, void* d_ws, size_t ws_size,
                              hipStream_t stream) {
  const float* x      = (const float*)d_in[0];
  const float* ln1_g  = (const float*)d_in[1];
  const float* ln1_b  = (const float*)d_in[2];
  const float* w_qkv  = (const float*)d_in[3];
  const float* b_qkv  = (const float*)d_in[4];
  const float* w_proj = (const float*)d_in[5];
  const float* b_proj = (const float*)d_in[6];
  const float* ln2_g  = (const float*)d_in[7];
  const float* ln2_b  = (const float*)d_in[8];
  const float* w_fc1  = (const float*)d_in[9];
  const float* b_fc1  = (const float*)d_in[10];
  const float* w_fc2  = (const float*)d_in[11];
  const float* b_fc2  = (const float*)d_in[12];
  float* out = (float*)d_out;

  char* p = (char*)d_ws;
  unsigned short* wqkvT  = (unsigned short*)p; p += (size_t)2304 * 768 * 2;
  unsigned short* wprojT = (unsigned short*)p; p += (size_t)768 * 768 * 2;
  unsigned short* wfc1T  = (unsigned short*)p; p += (size_t)3072 * 768 * 2;
  unsigned short* wfc2T  = (unsigned short*)p; p += (size_t)768 * 3072 * 2;
  unsigned short* h1     = (unsigned short*)p; p += (size_t)NTOK * 768 * 2;
  float*          x1     = (float*)p;          p += (size_t)NTOK * 768 * 4;
  unsigned short* qkv    = (unsigned short*)p; p += (size_t)NTOK * 2304 * 2;
  unsigned short* ob     = (unsigned short*)p; p += (size_t)NTOK * 768 * 2;
  unsigned short* g      = qkv;            // alias: qkv region, dead by FC1
  unsigned short* vT     = (unsigned short*)x1;  // alias: x1 dead until proj GEMM; vT dead after attn

  dim3 tb(32, 8);
  wtrans<<<dim3(2304 / 32, 768 / 32), tb, 0, stream>>>(w_qkv, wqkvT, 768, 2304);
  wtrans<<<dim3(768 / 32, 768 / 32), tb, 0, stream>>>(w_proj, wprojT, 768, 768);
  wtrans<<<dim3(3072 / 32, 768 / 32), tb, 0, stream>>>(w_fc1, wfc1T, 768, 3072);
  wtrans<<<dim3(768 / 32, 3072 / 32), tb, 0, stream>>>(w_fc2, wfc2T, 3072, 768);

  ln_768<<<NTOK, 256, 0, stream>>>(x, ln1_g, ln1_b, h1);
  gemm_bt<128, 0, 0, 1><<<dim3(18, 64), 256, 0, stream>>>(h1, wqkvT, b_qkv, nullptr, nullptr,
                                                          qkv, NTOK, 2304, 768);
  vtrans<<<dim3(24, 32, 8), tb, 0, stream>>>(qkv, vT);
  attn<<<dim3(16, 12, 8), 256, 0, stream>>>(qkv, vT, ob);
  gemm_bt<64, 0, 1, 0><<<dim3(12, 64), 256, 0, stream>>>(ob, wprojT, b_proj, x, x1, nullptr,
                                                         NTOK, 768, 768);
  ln_768<<<NTOK, 256, 0, stream>>>(x1, ln2_g, ln2_b, h1);
  gemm_bt<128, 1, 0, 1><<<dim3(24, 64), 256, 0, stream>>>(h1, wfc1T, b_fc1, nullptr, nullptr,
                                                          g, NTOK, 3072, 768);
  gemm_bt<64, 0, 1, 0><<<dim3(12, 64), 256, 0, stream>>>(g, wfc2T, b_fc2, x1, out, nullptr,
                                                         NTOK, 768, 3072);
}

// Round 10
// 291.878 us; speedup vs baseline: 1.3533x; 1.0756x over previous
//
#include <hip/hip_runtime.h>
#include <hip/hip_bf16.h>

typedef __attribute__((ext_vector_type(8))) short short8;
typedef __attribute__((ext_vector_type(4))) float f32x4;
typedef __attribute__((ext_vector_type(4))) unsigned short us4;

#define DIMC 768
#define HIDDENC 3072
#define NTOK 8192
#define SEQ 1024
#define NHEAD 12
#define HDIM 64

__device__ inline unsigned short f2bf(float f) {
  union { float f; unsigned u; } x; x.f = f;
  unsigned r = (x.u + 0x7FFFu + ((x.u >> 16) & 1u)) >> 16;
  return (unsigned short)r;
}

__device__ inline void gload_lds16(const void* g, void* lds) {
  __builtin_amdgcn_global_load_lds((const __attribute__((address_space(1))) unsigned*)g,
                                   (__attribute__((address_space(3))) unsigned*)lds, 16, 0, 0);
}

__device__ inline float gelu_fast(float u) {
  // gelu(u) ~= u * sigmoid(1.595769f*(u + 0.044715f*u^3)); inf-safe.
  const float c2u = u * (1.5957691216f + 0.0713548162f * u * u);
  return u - u * __builtin_amdgcn_rcpf(__expf(c2u) + 1.0f);
}

// ---------------- weight transpose + fp32->bf16 ----------------
// W: [K][N] f32  ->  Wt: [N][K] bf16
__global__ void wtrans(const float* __restrict__ W, unsigned short* __restrict__ Wt,
                       int K, int N) {
  __shared__ float tile[32][33];
  const int bx = blockIdx.x * 32;  // N
  const int by = blockIdx.y * 32;  // K
  const int tx = threadIdx.x, ty = threadIdx.y;
#pragma unroll
  for (int i = 0; i < 32; i += 8) tile[ty + i][tx] = W[(size_t)(by + ty + i) * N + bx + tx];
  __syncthreads();
#pragma unroll
  for (int i = 0; i < 32; i += 8)
    Wt[(size_t)(bx + ty + i) * K + by + tx] = f2bf(tile[tx][ty + i]);
}

// ---------------- V transpose: qkv V-part -> vT[b*768 + (h*64+d)][n] ----------------
__global__ void vtrans(const unsigned short* __restrict__ qkv, unsigned short* __restrict__ vT) {
  __shared__ unsigned short tile[32][33];
  const int bc = blockIdx.x * 32;  // c in [0,768)
  const int bn = blockIdx.y * 32;  // n in [0,1024)
  const int b = blockIdx.z;
  const int tx = threadIdx.x, ty = threadIdx.y;
#pragma unroll
  for (int i = 0; i < 32; i += 8)
    tile[ty + i][tx] = qkv[(size_t)(b * SEQ + bn + ty + i) * (3 * DIMC) + 2 * DIMC + bc + tx];
  __syncthreads();
#pragma unroll
  for (int i = 0; i < 32; i += 8)
    vT[(size_t)(b * DIMC + bc + ty + i) * SEQ + bn + tx] = tile[tx][ty + i];
}

// ---------------- LayerNorm over 768, f32 in -> bf16 out ----------------
__global__ __launch_bounds__(256) void ln_768(const float* __restrict__ x,
                                              const float* __restrict__ g,
                                              const float* __restrict__ b,
                                              unsigned short* __restrict__ out) {
  const int row = blockIdx.x;
  const int t = threadIdx.x;
  const float* xr = x + (size_t)row * DIMC;
  float v0 = xr[t], v1 = xr[t + 256], v2 = xr[t + 512];
  float s = v0 + v1 + v2;
  float ss = v0 * v0 + v1 * v1 + v2 * v2;
#pragma unroll
  for (int m = 1; m < 64; m <<= 1) { s += __shfl_xor(s, m); ss += __shfl_xor(ss, m); }
  __shared__ float red[8];
  const int w = t >> 6, l = t & 63;
  if (l == 0) { red[w] = s; red[4 + w] = ss; }
  __syncthreads();
  s = red[0] + red[1] + red[2] + red[3];
  ss = red[4] + red[5] + red[6] + red[7];
  const float mu = s * (1.0f / 768.0f);
  const float var = ss * (1.0f / 768.0f) - mu * mu;
  const float rstd = rsqrtf(var + 1e-5f);
  out[(size_t)row * DIMC + t]       = f2bf((v0 - mu) * rstd * g[t]       + b[t]);
  out[(size_t)row * DIMC + t + 256] = f2bf((v1 - mu) * rstd * g[t + 256] + b[t + 256]);
  out[(size_t)row * DIMC + t + 512] = f2bf((v2 - mu) * rstd * g[t + 512] + b[t + 512]);
}

// ---------------- GEMM v4 (BM=128, BN in {128,64}, BK=32): 2-phase dbuf + XOR-slot LDS ----
// Used for QKV and FC1 (big-N). See round-9 notes: coalesced staging + conflict-free reads.
template <int BN, int GELU, int RES, int OUT_BF16>
__global__ __launch_bounds__(256) void gemm_bt(const unsigned short* __restrict__ A,
                                               const unsigned short* __restrict__ Bt,
                                               const float* __restrict__ bias,
                                               const float* __restrict__ res,
                                               float* __restrict__ Cf,
                                               unsigned short* __restrict__ Cb,
                                               int M, int N, int K) {
  constexpr int NJ = BN / 32;
  __shared__ __align__(16) unsigned short As[2][128 * 32];
  __shared__ __align__(16) unsigned short Bs[2][BN * 32];
  const int gx = gridDim.x;
  const int nwg = gx * gridDim.y;
  const int orig = blockIdx.y * gx + blockIdx.x;
  const int cpx = nwg >> 3;                       // nwg % 8 == 0
  const int wg = (orig & 7) * cpx + (orig >> 3);
  const int bxx = wg % gx, byy = wg / gx;
  const int t = threadIdx.x;
  const int w = t >> 6, l = t & 63;
  const int lr = l & 15, lg = l >> 4;
  const int wr = w >> 1, wc = w & 1;
  const unsigned short* Ag = A + (size_t)byy * 128 * K;
  const unsigned short* Bg = Bt + (size_t)bxx * BN * K;
  const int kc1 = (t & 3) ^ ((t >> 3) & 3);
  const size_t a1 = (size_t)(t >> 2) * K + (size_t)kc1 * 8;
  const size_t a2 = a1 + (size_t)64 * K;
  const int fx = (lg ^ ((lr >> 1) & 3)) * 16;
  f32x4 acc[4][NJ] = {};

  auto stage = [&](int buf, int k0) {
    gload_lds16(Ag + a1 + k0, &As[buf][w * 512]);
    gload_lds16(Ag + a2 + k0, &As[buf][2048 + w * 512]);
    gload_lds16(Bg + a1 + k0, &Bs[buf][w * 512]);
    if (BN == 128) gload_lds16(Bg + a2 + k0, &Bs[buf][2048 + w * 512]);
  };
  auto compute = [&](int buf) {
    short8 af[4], bf[NJ];
#pragma unroll
    for (int i = 0; i < 4; i++)
      af[i] = *(const short8*)((const char*)&As[buf][0] +
                               (size_t)(wr * 64 + i * 16 + lr) * 64 + fx);
#pragma unroll
    for (int j = 0; j < NJ; j++)
      bf[j] = *(const short8*)((const char*)&Bs[buf][0] +
                               (size_t)(wc * (16 * NJ) + j * 16 + lr) * 64 + fx);
#pragma unroll
    for (int i = 0; i < 4; i++)
#pragma unroll
      for (int j = 0; j < NJ; j++)
        acc[i][j] = __builtin_amdgcn_mfma_f32_16x16x32_bf16(af[i], bf[j], acc[i][j], 0, 0, 0);
  };

  const int nt = K >> 5;
  stage(0, 0);
  __syncthreads();
  for (int tt = 0; tt < nt; tt += 2) {
    stage(1, (tt + 1) << 5);
    compute(0);
    __syncthreads();
    if (tt + 2 < nt) stage(0, (tt + 2) << 5);
    compute(1);
    __syncthreads();
  }

  const int rbase = byy * 128 + wr * 64;
  const int cbase = bxx * BN + wc * (16 * NJ);
#pragma unroll
  for (int i = 0; i < 4; i++)
#pragma unroll
    for (int j = 0; j < NJ; j++) {
      const int c = cbase + j * 16 + lr;
      const float bz = bias[c];
#pragma unroll
      for (int v = 0; v < 4; v++) {
        const int r = rbase + i * 16 + lg * 4 + v;
        float val = acc[i][j][v] + bz;
        if (RES) val += res[(size_t)r * N + c];
        if (GELU) val = gelu_fast(val);
        if (OUT_BF16) Cb[(size_t)r * N + c] = f2bf(val);
        else          Cf[(size_t)r * N + c] = val;
      }
    }
}

// ---------------- GEMM v5 (BM=64, BN=128, BK=64): small-N shape for proj/FC2 ----------------
// 4 waves (1M x 4N): wave w computes rows 0..63 x cols w*32..w*32+31 -> 4x2 frags x 2 kc
// = 16 MFMA per barrier. Grid (N/128, M/64): N=768 -> 768 blocks = 3/CU. LDS 48KB = 3/CU.
// LDS rows are 128B (64 k-elems); swizzle byte ^= (row&7)<<4 (attn-verified, 0 conflicts),
// staged via inverse-permuted global source (unit_log = (slot&7)^(row&7) stays in-line-pair).
template <int GELU, int RES, int OUT_BF16>
__global__ __launch_bounds__(256) void gemm_bt64(const unsigned short* __restrict__ A,
                                                 const unsigned short* __restrict__ Bt,
                                                 const float* __restrict__ bias,
                                                 const float* __restrict__ res,
                                                 float* __restrict__ Cf,
                                                 unsigned short* __restrict__ Cb,
                                                 int M, int N, int K) {
  __shared__ __align__(16) unsigned short As[2][64 * 64];    // 8KB/buf
  __shared__ __align__(16) unsigned short Bs[2][128 * 64];   // 16KB/buf
  const int gx = gridDim.x;
  const int nwg = gx * gridDim.y;
  const int orig = blockIdx.y * gx + blockIdx.x;
  const int cpx = nwg >> 3;                       // nwg % 8 == 0
  const int wg = (orig & 7) * cpx + (orig >> 3);
  const int bxx = wg % gx, byy = wg / gx;
  const int t = threadIdx.x;
  const int w = t >> 6, l = t & 63;
  const int lr = l & 15, lg = l >> 4;
  const unsigned short* Ag = A + (size_t)byy * 64 * K;
  const unsigned short* Bg = Bt + (size_t)bxx * 128 * K;
  // slot s: row = s>>3, stored unit = s&7, logical unit = (s&7)^(row&7)
  const int srow = t >> 3;
  const int sulog = (t & 7) ^ (srow & 7);
  const size_t sa = (size_t)srow * K + (size_t)sulog * 8;   // +32*K per 256-slot group
  f32x4 acc[4][2] = {};

  auto stage = [&](int buf, int k0) {
    gload_lds16(Ag + sa + k0, &As[buf][w * 512]);
    gload_lds16(Ag + sa + (size_t)32 * K + k0, &As[buf][2048 + w * 512]);
    gload_lds16(Bg + sa + k0, &Bs[buf][w * 512]);
    gload_lds16(Bg + sa + (size_t)32 * K + k0, &Bs[buf][2048 + w * 512]);
    gload_lds16(Bg + sa + (size_t)64 * K + k0, &Bs[buf][4096 + w * 512]);
    gload_lds16(Bg + sa + (size_t)96 * K + k0, &Bs[buf][6144 + w * 512]);
  };
  auto compute = [&](int buf) {
#pragma unroll
    for (int kc = 0; kc < 2; kc++) {
      const int ux = ((kc * 4 + lg) ^ (lr & 7)) * 16;   // row&7 == lr&7 (frag rows %16)
      short8 af[4], bf[2];
#pragma unroll
      for (int i = 0; i < 4; i++)
        af[i] = *(const short8*)((const char*)&As[buf][0] + (size_t)(i * 16 + lr) * 128 + ux);
#pragma unroll
      for (int j = 0; j < 2; j++)
        bf[j] = *(const short8*)((const char*)&Bs[buf][0] +
                                 (size_t)((w * 2 + j) * 16 + lr) * 128 + ux);
#pragma unroll
      for (int i = 0; i < 4; i++)
#pragma unroll
        for (int j = 0; j < 2; j++)
          acc[i][j] = __builtin_amdgcn_mfma_f32_16x16x32_bf16(af[i], bf[j], acc[i][j], 0, 0, 0);
    }
  };

  const int nt = K >> 6;  // proj: 12, FC2: 48 (even)
  stage(0, 0);
  __syncthreads();
  for (int tt = 0; tt < nt; tt += 2) {
    stage(1, (tt + 1) << 6);
    compute(0);
    __syncthreads();
    if (tt + 2 < nt) stage(0, (tt + 2) << 6);
    compute(1);
    __syncthreads();
  }

  const int rbase = byy * 64;
  const int cbase = bxx * 128 + w * 32;
#pragma unroll
  for (int i = 0; i < 4; i++)
#pragma unroll
    for (int j = 0; j < 2; j++) {
      const int c = cbase + j * 16 + lr;
      const float bz = bias[c];
#pragma unroll
      for (int v = 0; v < 4; v++) {
        const int r = rbase + i * 16 + lg * 4 + v;
        float val = acc[i][j][v] + bz;
        if (RES) val += res[(size_t)r * N + c];
        if (GELU) val = gelu_fast(val);
        if (OUT_BF16) Cb[(size_t)r * N + c] = f2bf(val);
        else          Cf[(size_t)r * N + c] = val;
      }
    }
}

// ---------------- fused attention (v5: swapped QK^T + T14 async K/V reg-prefetch) ----
__global__ __launch_bounds__(256) void attn(const unsigned short* __restrict__ qkv,
                                            const unsigned short* __restrict__ vT,
                                            unsigned short* __restrict__ o) {
  const int qt = blockIdx.x, h = blockIdx.y, b = blockIdx.z;
  const int t = threadIdx.x, w = t >> 6, l = t & 63;
  const int lr = l & 15, lg = l >> 4;
  const int ld = 3 * DIMC;
  __shared__ __align__(16) unsigned short Ks[64 * 64];
  __shared__ __align__(16) unsigned short Vt[64 * 64];
  __shared__ __align__(16) unsigned short Ps[4][16 * 64];

  const unsigned short* qb = qkv + (size_t)(b * SEQ + qt * 64 + w * 16) * ld + h * HDIM;
  short8 qf0 = *(const short8*)(qb + (size_t)lr * ld + lg * 8);        // Q rows q=lr (B-operand)
  short8 qf1 = *(const short8*)(qb + (size_t)lr * ld + 32 + lg * 8);

  const int r = t >> 2, c4 = (t & 3) * 16;
  const int sw = (r & 7) << 4;
  const unsigned short* kb_base = qkv + (size_t)(b * SEQ) * ld + DIMC + h * HDIM + (size_t)r * ld;
  const unsigned short* vrow = vT + (size_t)(b * DIMC + h * HDIM + r) * SEQ;

  short8 ck0 = *(const short8*)(kb_base + c4);
  short8 ck1 = *(const short8*)(kb_base + c4 + 8);
  short8 cv0 = *(const short8*)(vrow + c4);
  short8 cv1 = *(const short8*)(vrow + c4 + 8);

  float m_run = -1e30f, l_run = 0.f;
  f32x4 oacc[4];
#pragma unroll
  for (int i = 0; i < 4; i++) oacc[i] = (f32x4){0.f, 0.f, 0.f, 0.f};

  for (int kt = 0; kt < 16; ++kt) {
    {
      char* ksb = (char*)Ks + r * 128;
      *(short8*)(ksb + ((c4 * 2) ^ sw))      = ck0;
      *(short8*)(ksb + ((c4 * 2 + 16) ^ sw)) = ck1;
      char* vsb = (char*)Vt + r * 128;
      *(short8*)(vsb + ((c4 * 2) ^ sw))      = cv0;
      *(short8*)(vsb + ((c4 * 2 + 16) ^ sw)) = cv1;
    }
    const int nk = (kt + 1) & 15;
    short8 nk0 = *(const short8*)(kb_base + (size_t)nk * 64 * ld + c4);
    short8 nk1 = *(const short8*)(kb_base + (size_t)nk * 64 * ld + c4 + 8);
    short8 nv0 = *(const short8*)(vrow + nk * 64 + c4);
    short8 nv1 = *(const short8*)(vrow + nk * 64 + c4 + 8);

    asm volatile("s_waitcnt lgkmcnt(0)" ::: "memory");
    __builtin_amdgcn_s_barrier();
    __builtin_amdgcn_sched_barrier(0);

    f32x4 sf[4];
#pragma unroll
    for (int n = 0; n < 4; n++) sf[n] = (f32x4){0.f, 0.f, 0.f, 0.f};
#pragma unroll
    for (int kc = 0; kc < 2; kc++) {
      short8 q = kc ? qf1 : qf0;
#pragma unroll
      for (int n = 0; n < 4; n++) {
        const int row = n * 16 + lr;
        short8 kf = *(const short8*)((const char*)Ks + row * 128 +
                                     (((kc * 32 + lg * 8) * 2) ^ ((row & 7) << 4)));
        sf[n] = __builtin_amdgcn_mfma_f32_16x16x32_bf16(kf, q, sf[n], 0, 0, 0);
      }
    }

    float pv[4][4];
    float tmax = -1e30f;
#pragma unroll
    for (int n = 0; n < 4; n++)
#pragma unroll
      for (int v = 0; v < 4; v++) {
        float s = sf[n][v] * 0.125f;
        s = fminf(fmaxf(s, -50.f), 50.f);
        pv[n][v] = s;
        tmax = fmaxf(tmax, s);
      }
    tmax = fmaxf(tmax, __shfl_xor(tmax, 16));
    tmax = fmaxf(tmax, __shfl_xor(tmax, 32));
    const float mn = fmaxf(m_run, tmax);
    const float alpha = __expf(m_run - mn);
    m_run = mn;
    l_run *= alpha;
    float psum = 0.f;
    char* psw = (char*)&Ps[w][0] + lr * 128;
    const int psx = (lr & 7) << 4;
#pragma unroll
    for (int n = 0; n < 4; n++) {
      us4 pk;
#pragma unroll
      for (int v = 0; v < 4; v++) {
        float e = __expf(pv[n][v] - mn);
        psum += e;
        pk[v] = f2bf(e);
      }
      *(us4*)(psw + ((n * 32 + lg * 8) ^ psx)) = pk;
    }
    psum += __shfl_xor(psum, 16);
    psum += __shfl_xor(psum, 32);
    l_run += psum;

#pragma unroll
    for (int v = 0; v < 4; v++) {
      const float av = __shfl(alpha, lg * 4 + v);
#pragma unroll
      for (int dn = 0; dn < 4; dn++) oacc[dn][v] *= av;
    }

    asm volatile("s_waitcnt lgkmcnt(0)" ::: "memory");
    __builtin_amdgcn_sched_barrier(0);

#pragma unroll
    for (int kc = 0; kc < 2; kc++) {
      short8 pf = *(const short8*)((const char*)&Ps[w][0] + lr * 128 +
                                   (((kc * 32 + lg * 8) * 2) ^ ((lr & 7) << 4)));
#pragma unroll
      for (int dn = 0; dn < 4; dn++) {
        const int row = dn * 16 + lr;
        short8 vf = *(const short8*)((const char*)Vt + row * 128 +
                                     (((kc * 32 + lg * 8) * 2) ^ ((row & 7) << 4)));
        oacc[dn] = __builtin_amdgcn_mfma_f32_16x16x32_bf16(pf, vf, oacc[dn], 0, 0, 0);
      }
    }
    __builtin_amdgcn_sched_barrier(0);
    __builtin_amdgcn_s_barrier();
    ck0 = nk0; ck1 = nk1; cv0 = nv0; cv1 = nv1;
  }

  unsigned short* ob = o + (size_t)(b * SEQ + qt * 64 + w * 16) * DIMC + h * HDIM;
#pragma unroll
  for (int v = 0; v < 4; v++) {
    const float lv = __shfl(l_run, lg * 4 + v);
    const float inv = 1.0f / lv;
#pragma unroll
    for (int dn = 0; dn < 4; dn++)
      ob[(size_t)(lg * 4 + v) * DIMC + dn * 16 + lr] = f2bf(oacc[dn][v] * inv);
  }
}

extern "C" void kernel_launch(void* const* d_in, const int* in_sizes, int n_in,
                              void* d_out, int out_size, void* d_ws, size_t ws_size,
                              hipStream_t stream) {
  const float* x      = (const float*)d_in[0];
  const float* ln1_g  = (const float*)d_in[1];
  const float* ln1_b  = (const float*)d_in[2];
  const float* w_qkv  = (const float*)d_in[3];
  const float* b_qkv  = (const float*)d_in[4];
  const float* w_proj = (const float*)d_in[5];
  const float* b_proj = (const float*)d_in[6];
  const float* ln2_g  = (const float*)d_in[7];
  const float* ln2_b  = (const float*)d_in[8];
  const float* w_fc1  = (const float*)d_in[9];
  const float* b_fc1  = (const float*)d_in[10];
  const float* w_fc2  = (const float*)d_in[11];
  const float* b_fc2  = (const float*)d_in[12];
  float* out = (float*)d_out;

  char* p = (char*)d_ws;
  unsigned short* wqkvT  = (unsigned short*)p; p += (size_t)2304 * 768 * 2;
  unsigned short* wprojT = (unsigned short*)p; p += (size_t)768 * 768 * 2;
  unsigned short* wfc1T  = (unsigned short*)p; p += (size_t)3072 * 768 * 2;
  unsigned short* wfc2T  = (unsigned short*)p; p += (size_t)768 * 3072 * 2;
  unsigned short* h1     = (unsigned short*)p; p += (size_t)NTOK * 768 * 2;
  float*          x1     = (float*)p;          p += (size_t)NTOK * 768 * 4;
  unsigned short* qkv    = (unsigned short*)p; p += (size_t)NTOK * 2304 * 2;
  unsigned short* ob     = (unsigned short*)p; p += (size_t)NTOK * 768 * 2;
  unsigned short* g      = qkv;            // alias: qkv region, dead by FC1
  unsigned short* vT     = (unsigned short*)x1;  // alias: x1 dead until proj GEMM; vT dead after attn

  dim3 tb(32, 8);
  wtrans<<<dim3(2304 / 32, 768 / 32), tb, 0, stream>>>(w_qkv, wqkvT, 768, 2304);
  wtrans<<<dim3(768 / 32, 768 / 32), tb, 0, stream>>>(w_proj, wprojT, 768, 768);
  wtrans<<<dim3(3072 / 32, 768 / 32), tb, 0, stream>>>(w_fc1, wfc1T, 768, 3072);
  wtrans<<<dim3(768 / 32, 3072 / 32), tb, 0, stream>>>(w_fc2, wfc2T, 3072, 768);

  ln_768<<<NTOK, 256, 0, stream>>>(x, ln1_g, ln1_b, h1);
  gemm_bt<128, 0, 0, 1><<<dim3(18, 64), 256, 0, stream>>>(h1, wqkvT, b_qkv, nullptr, nullptr,
                                                          qkv, NTOK, 2304, 768);
  vtrans<<<dim3(24, 32, 8), tb, 0, stream>>>(qkv, vT);
  attn<<<dim3(16, 12, 8), 256, 0, stream>>>(qkv, vT, ob);
  gemm_bt64<0, 1, 0><<<dim3(6, 128), 256, 0, stream>>>(ob, wprojT, b_proj, x, x1, nullptr,
                                                       NTOK, 768, 768);
  ln_768<<<NTOK, 256, 0, stream>>>(x1, ln2_g, ln2_b, h1);
  gemm_bt<128, 1, 0, 1><<<dim3(24, 64), 256, 0, stream>>>(h1, wfc1T, b_fc1, nullptr, nullptr,
                                                          g, NTOK, 3072, 768);
  gemm_bt64<0, 1, 0><<<dim3(6, 128), 256, 0, stream>>>(g, wfc2T, b_fc2, x1, out, nullptr,
                                                       NTOK, 768, 3072);
}

// Round 11
// 290.175 us; speedup vs baseline: 1.3612x; 1.0059x over previous
//
#include <hip/hip_runtime.h>
#include <hip/hip_bf16.h>

typedef __attribute__((ext_vector_type(8))) short short8;
typedef __attribute__((ext_vector_type(4))) float f32x4;
typedef __attribute__((ext_vector_type(4))) unsigned short us4;

#define DIMC 768
#define HIDDENC 3072
#define NTOK 8192
#define SEQ 1024
#define NHEAD 12
#define HDIM 64

__device__ inline unsigned short f2bf(float f) {
  union { float f; unsigned u; } x; x.f = f;
  unsigned r = (x.u + 0x7FFFu + ((x.u >> 16) & 1u)) >> 16;
  return (unsigned short)r;
}

__device__ inline void gload_lds16(const void* g, void* lds) {
  __builtin_amdgcn_global_load_lds((const __attribute__((address_space(1))) unsigned*)g,
                                   (__attribute__((address_space(3))) unsigned*)lds, 16, 0, 0);
}

__device__ inline float gelu_fast(float u) {
  // gelu(u) ~= u * sigmoid(1.595769f*(u + 0.044715f*u^3)); inf-safe.
  const float c2u = u * (1.5957691216f + 0.0713548162f * u * u);
  return u - u * __builtin_amdgcn_rcpf(__expf(c2u) + 1.0f);
}

// ---------------- weight transpose + fp32->bf16 ----------------
// W: [K][N] f32  ->  Wt: [N][K] bf16
__global__ void wtrans(const float* __restrict__ W, unsigned short* __restrict__ Wt,
                       int K, int N) {
  __shared__ float tile[32][33];
  const int bx = blockIdx.x * 32;  // N
  const int by = blockIdx.y * 32;  // K
  const int tx = threadIdx.x, ty = threadIdx.y;
#pragma unroll
  for (int i = 0; i < 32; i += 8) tile[ty + i][tx] = W[(size_t)(by + ty + i) * N + bx + tx];
  __syncthreads();
#pragma unroll
  for (int i = 0; i < 32; i += 8)
    Wt[(size_t)(bx + ty + i) * K + by + tx] = f2bf(tile[tx][ty + i]);
}

// ---------------- V transpose: qkv V-part -> vT[b*768 + (h*64+d)][n] ----------------
__global__ void vtrans(const unsigned short* __restrict__ qkv, unsigned short* __restrict__ vT) {
  __shared__ unsigned short tile[32][33];
  const int bc = blockIdx.x * 32;  // c in [0,768)
  const int bn = blockIdx.y * 32;  // n in [0,1024)
  const int b = blockIdx.z;
  const int tx = threadIdx.x, ty = threadIdx.y;
#pragma unroll
  for (int i = 0; i < 32; i += 8)
    tile[ty + i][tx] = qkv[(size_t)(b * SEQ + bn + ty + i) * (3 * DIMC) + 2 * DIMC + bc + tx];
  __syncthreads();
#pragma unroll
  for (int i = 0; i < 32; i += 8)
    vT[(size_t)(b * DIMC + bc + ty + i) * SEQ + bn + tx] = tile[tx][ty + i];
}

// ---------------- LayerNorm over 768, f32 in -> bf16 out ----------------
__global__ __launch_bounds__(256) void ln_768(const float* __restrict__ x,
                                              const float* __restrict__ g,
                                              const float* __restrict__ b,
                                              unsigned short* __restrict__ out) {
  const int row = blockIdx.x;
  const int t = threadIdx.x;
  const float* xr = x + (size_t)row * DIMC;
  float v0 = xr[t], v1 = xr[t + 256], v2 = xr[t + 512];
  float s = v0 + v1 + v2;
  float ss = v0 * v0 + v1 * v1 + v2 * v2;
#pragma unroll
  for (int m = 1; m < 64; m <<= 1) { s += __shfl_xor(s, m); ss += __shfl_xor(ss, m); }
  __shared__ float red[8];
  const int w = t >> 6, l = t & 63;
  if (l == 0) { red[w] = s; red[4 + w] = ss; }
  __syncthreads();
  s = red[0] + red[1] + red[2] + red[3];
  ss = red[4] + red[5] + red[6] + red[7];
  const float mu = s * (1.0f / 768.0f);
  const float var = ss * (1.0f / 768.0f) - mu * mu;
  const float rstd = rsqrtf(var + 1e-5f);
  out[(size_t)row * DIMC + t]       = f2bf((v0 - mu) * rstd * g[t]       + b[t]);
  out[(size_t)row * DIMC + t + 256] = f2bf((v1 - mu) * rstd * g[t + 256] + b[t + 256]);
  out[(size_t)row * DIMC + t + 512] = f2bf((v2 - mu) * rstd * g[t + 512] + b[t + 512]);
}

// ---------------- GEMM v4 (BM=128, BN in {128,64}, BK=32): 2-phase dbuf + XOR-slot LDS ----
// Used for QKV and FC1 (big-N). Coalesced staging + conflict-free reads (round-9 verified).
template <int BN, int GELU, int RES, int OUT_BF16>
__global__ __launch_bounds__(256) void gemm_bt(const unsigned short* __restrict__ A,
                                               const unsigned short* __restrict__ Bt,
                                               const float* __restrict__ bias,
                                               const float* __restrict__ res,
                                               float* __restrict__ Cf,
                                               unsigned short* __restrict__ Cb,
                                               int M, int N, int K) {
  constexpr int NJ = BN / 32;
  __shared__ __align__(16) unsigned short As[2][128 * 32];
  __shared__ __align__(16) unsigned short Bs[2][BN * 32];
  const int gx = gridDim.x;
  const int nwg = gx * gridDim.y;
  const int orig = blockIdx.y * gx + blockIdx.x;
  const int cpx = nwg >> 3;                       // nwg % 8 == 0
  const int wg = (orig & 7) * cpx + (orig >> 3);
  const int bxx = wg % gx, byy = wg / gx;
  const int t = threadIdx.x;
  const int w = t >> 6, l = t & 63;
  const int lr = l & 15, lg = l >> 4;
  const int wr = w >> 1, wc = w & 1;
  const unsigned short* Ag = A + (size_t)byy * 128 * K;
  const unsigned short* Bg = Bt + (size_t)bxx * BN * K;
  const int kc1 = (t & 3) ^ ((t >> 3) & 3);
  const size_t a1 = (size_t)(t >> 2) * K + (size_t)kc1 * 8;
  const size_t a2 = a1 + (size_t)64 * K;
  const int fx = (lg ^ ((lr >> 1) & 3)) * 16;
  f32x4 acc[4][NJ] = {};

  auto stage = [&](int buf, int k0) {
    gload_lds16(Ag + a1 + k0, &As[buf][w * 512]);
    gload_lds16(Ag + a2 + k0, &As[buf][2048 + w * 512]);
    gload_lds16(Bg + a1 + k0, &Bs[buf][w * 512]);
    if (BN == 128) gload_lds16(Bg + a2 + k0, &Bs[buf][2048 + w * 512]);
  };
  auto compute = [&](int buf) {
    short8 af[4], bf[NJ];
#pragma unroll
    for (int i = 0; i < 4; i++)
      af[i] = *(const short8*)((const char*)&As[buf][0] +
                               (size_t)(wr * 64 + i * 16 + lr) * 64 + fx);
#pragma unroll
    for (int j = 0; j < NJ; j++)
      bf[j] = *(const short8*)((const char*)&Bs[buf][0] +
                               (size_t)(wc * (16 * NJ) + j * 16 + lr) * 64 + fx);
#pragma unroll
    for (int i = 0; i < 4; i++)
#pragma unroll
      for (int j = 0; j < NJ; j++)
        acc[i][j] = __builtin_amdgcn_mfma_f32_16x16x32_bf16(af[i], bf[j], acc[i][j], 0, 0, 0);
  };

  const int nt = K >> 5;
  stage(0, 0);
  __syncthreads();
  for (int tt = 0; tt < nt; tt += 2) {
    stage(1, (tt + 1) << 5);
    compute(0);
    __syncthreads();
    if (tt + 2 < nt) stage(0, (tt + 2) << 5);
    compute(1);
    __syncthreads();
  }

  const int rbase = byy * 128 + wr * 64;
  const int cbase = bxx * BN + wc * (16 * NJ);
#pragma unroll
  for (int i = 0; i < 4; i++)
#pragma unroll
    for (int j = 0; j < NJ; j++) {
      const int c = cbase + j * 16 + lr;
      const float bz = bias[c];
#pragma unroll
      for (int v = 0; v < 4; v++) {
        const int r = rbase + i * 16 + lg * 4 + v;
        float val = acc[i][j][v] + bz;
        if (RES) val += res[(size_t)r * N + c];
        if (GELU) val = gelu_fast(val);
        if (OUT_BF16) Cb[(size_t)r * N + c] = f2bf(val);
        else          Cf[(size_t)r * N + c] = val;
      }
    }
}

// ---------------- GEMM v5 (BM=64, BN=128, BK=64): small-N shape for proj/FC2 ----------------
template <int GELU, int RES, int OUT_BF16>
__global__ __launch_bounds__(256) void gemm_bt64(const unsigned short* __restrict__ A,
                                                 const unsigned short* __restrict__ Bt,
                                                 const float* __restrict__ bias,
                                                 const float* __restrict__ res,
                                                 float* __restrict__ Cf,
                                                 unsigned short* __restrict__ Cb,
                                                 int M, int N, int K) {
  __shared__ __align__(16) unsigned short As[2][64 * 64];
  __shared__ __align__(16) unsigned short Bs[2][128 * 64];
  const int gx = gridDim.x;
  const int nwg = gx * gridDim.y;
  const int orig = blockIdx.y * gx + blockIdx.x;
  const int cpx = nwg >> 3;                       // nwg % 8 == 0
  const int wg = (orig & 7) * cpx + (orig >> 3);
  const int bxx = wg % gx, byy = wg / gx;
  const int t = threadIdx.x;
  const int w = t >> 6, l = t & 63;
  const int lr = l & 15, lg = l >> 4;
  const unsigned short* Ag = A + (size_t)byy * 64 * K;
  const unsigned short* Bg = Bt + (size_t)bxx * 128 * K;
  const int srow = t >> 3;
  const int sulog = (t & 7) ^ (srow & 7);
  const size_t sa = (size_t)srow * K + (size_t)sulog * 8;
  f32x4 acc[4][2] = {};

  auto stage = [&](int buf, int k0) {
    gload_lds16(Ag + sa + k0, &As[buf][w * 512]);
    gload_lds16(Ag + sa + (size_t)32 * K + k0, &As[buf][2048 + w * 512]);
    gload_lds16(Bg + sa + k0, &Bs[buf][w * 512]);
    gload_lds16(Bg + sa + (size_t)32 * K + k0, &Bs[buf][2048 + w * 512]);
    gload_lds16(Bg + sa + (size_t)64 * K + k0, &Bs[buf][4096 + w * 512]);
    gload_lds16(Bg + sa + (size_t)96 * K + k0, &Bs[buf][6144 + w * 512]);
  };
  auto compute = [&](int buf) {
#pragma unroll
    for (int kc = 0; kc < 2; kc++) {
      const int ux = ((kc * 4 + lg) ^ (lr & 7)) * 16;
      short8 af[4], bf[2];
#pragma unroll
      for (int i = 0; i < 4; i++)
        af[i] = *(const short8*)((const char*)&As[buf][0] + (size_t)(i * 16 + lr) * 128 + ux);
#pragma unroll
      for (int j = 0; j < 2; j++)
        bf[j] = *(const short8*)((const char*)&Bs[buf][0] +
                                 (size_t)((w * 2 + j) * 16 + lr) * 128 + ux);
#pragma unroll
      for (int i = 0; i < 4; i++)
#pragma unroll
        for (int j = 0; j < 2; j++)
          acc[i][j] = __builtin_amdgcn_mfma_f32_16x16x32_bf16(af[i], bf[j], acc[i][j], 0, 0, 0);
    }
  };

  const int nt = K >> 6;
  stage(0, 0);
  __syncthreads();
  for (int tt = 0; tt < nt; tt += 2) {
    stage(1, (tt + 1) << 6);
    compute(0);
    __syncthreads();
    if (tt + 2 < nt) stage(0, (tt + 2) << 6);
    compute(1);
    __syncthreads();
  }

  const int rbase = byy * 64;
  const int cbase = bxx * 128 + w * 32;
#pragma unroll
  for (int i = 0; i < 4; i++)
#pragma unroll
    for (int j = 0; j < 2; j++) {
      const int c = cbase + j * 16 + lr;
      const float bz = bias[c];
#pragma unroll
      for (int v = 0; v < 4; v++) {
        const int r = rbase + i * 16 + lg * 4 + v;
        float val = acc[i][j][v] + bz;
        if (RES) val += res[(size_t)r * N + c];
        if (GELU) val = gelu_fast(val);
        if (OUT_BF16) Cb[(size_t)r * N + c] = f2bf(val);
        else          Cf[(size_t)r * N + c] = val;
      }
    }
}

// ---------------- fused attention (v6: KVBLK=128) ----------------
// qkv bf16 [8192][2304]; vT bf16 [8*768][1024]; o bf16 [8192][768]
// grid (16 qtiles, 12 heads, 8 batch), 256 threads (4 waves, 16 q-rows each)
// KV tile = 128 keys: halves barriers + softmax bookkeeping per key vs KVBLK=64.
// Ks[128][64] (128B rows), Vt[64][128] (256B rows), Ps[4][16][128] (256B rows);
// all swizzled byte_in_row ^= (row&7)<<4  (<=2-way on every access: free).
__global__ __launch_bounds__(256) void attn(const unsigned short* __restrict__ qkv,
                                            const unsigned short* __restrict__ vT,
                                            unsigned short* __restrict__ o) {
  const int qt = blockIdx.x, h = blockIdx.y, b = blockIdx.z;
  const int t = threadIdx.x, w = t >> 6, l = t & 63;
  const int lr = l & 15, lg = l >> 4;
  const int ld = 3 * DIMC;
  __shared__ __align__(16) unsigned short Ks[128 * 64];
  __shared__ __align__(16) unsigned short Vt[64 * 128];
  __shared__ __align__(16) unsigned short Ps[4][16 * 128];

  const unsigned short* qb = qkv + (size_t)(b * SEQ + qt * 64 + w * 16) * ld + h * HDIM;
  short8 qf0 = *(const short8*)(qb + (size_t)lr * ld + lg * 8);        // Q rows q=lr (B-operand)
  short8 qf1 = *(const short8*)(qb + (size_t)lr * ld + 32 + lg * 8);

  // K staging: thread t -> key-row rk = t>>1 (of 128), 64B segment seg = t&1
  const int rk = t >> 1, seg = t & 1;
  const unsigned short* kb_base = qkv + (size_t)(b * SEQ + rk) * ld + DIMC + h * HDIM + seg * 32;
  // V staging: thread t -> d-row dv = t>>2 (of 64), 64B segment seg4 = t&3
  const int dv = t >> 2, seg4 = t & 3;
  const unsigned short* vrow = vT + (size_t)(b * DIMC + h * HDIM + dv) * SEQ + seg4 * 32;

  // staging regs for current tile (kt=0)
  short8 ck[4], cv[4];
#pragma unroll
  for (int j = 0; j < 4; j++) ck[j] = *(const short8*)(kb_base + j * 8);
#pragma unroll
  for (int j = 0; j < 4; j++) cv[j] = *(const short8*)(vrow + j * 8);

  float m_run = -1e30f, l_run = 0.f;   // stats for q = w*16 + lr (replicated over lg)
  f32x4 oacc[4];                       // O[q=lg*4+v][d=dn*16+lr]
#pragma unroll
  for (int i = 0; i < 4; i++) oacc[i] = (f32x4){0.f, 0.f, 0.f, 0.f};

  for (int kt = 0; kt < 8; ++kt) {
    // ---- write current K/V tile to LDS (swizzled) ----
    {
      char* ksb = (char*)Ks + rk * 128;
      const int swk = (rk & 7) << 4;
#pragma unroll
      for (int j = 0; j < 4; j++)
        *(short8*)(ksb + ((seg * 64 + j * 16) ^ swk)) = ck[j];
      char* vsb = (char*)Vt + dv * 256;
      const int swv = (dv & 7) << 4;
#pragma unroll
      for (int j = 0; j < 4; j++)
        *(short8*)(vsb + ((seg4 * 64 + j * 16) ^ swv)) = cv[j];
    }
    // ---- prefetch next tile into regs (wrapped; last iter wasted but valid) ----
    const int nk = (kt + 1) & 7;
    short8 nkk[4], nvv[4];
#pragma unroll
    for (int j = 0; j < 4; j++)
      nkk[j] = *(const short8*)(kb_base + (size_t)nk * 128 * ld + j * 8);
#pragma unroll
    for (int j = 0; j < 4; j++)
      nvv[j] = *(const short8*)(vrow + nk * 128 + j * 8);

    asm volatile("s_waitcnt lgkmcnt(0)" ::: "memory");  // K/V ds_writes visible
    __builtin_amdgcn_s_barrier();
    __builtin_amdgcn_sched_barrier(0);

    // ---- swapped QK^T: sf[n][v] = S[q=lr][k=n*16+lg*4+v], n=0..7 ----
    f32x4 sf[8];
#pragma unroll
    for (int n = 0; n < 8; n++) sf[n] = (f32x4){0.f, 0.f, 0.f, 0.f};
#pragma unroll
    for (int kc = 0; kc < 2; kc++) {
      short8 q = kc ? qf1 : qf0;
#pragma unroll
      for (int n = 0; n < 8; n++) {
        const int row = n * 16 + lr;
        short8 kf = *(const short8*)((const char*)Ks + row * 128 +
                                     (((kc * 32 + lg * 8) * 2) ^ ((row & 7) << 4)));
        sf[n] = __builtin_amdgcn_mfma_f32_16x16x32_bf16(kf, q, sf[n], 0, 0, 0);
      }
    }

    // ---- online softmax, q = lr local; clamp in place ----
    float tmax = -1e30f;
#pragma unroll
    for (int n = 0; n < 8; n++)
#pragma unroll
      for (int v = 0; v < 4; v++) {
        float s = sf[n][v] * 0.125f;
        s = fminf(fmaxf(s, -50.f), 50.f);
        sf[n][v] = s;
        tmax = fmaxf(tmax, s);
      }
    tmax = fmaxf(tmax, __shfl_xor(tmax, 16));
    tmax = fmaxf(tmax, __shfl_xor(tmax, 32));
    const float mn = fmaxf(m_run, tmax);
    const float alpha = __expf(m_run - mn);
    m_run = mn;
    l_run *= alpha;
    float psum = 0.f;
    char* psw = (char*)&Ps[w][0] + lr * 256;
    const int psx = (lr & 7) << 4;
#pragma unroll
    for (int n = 0; n < 8; n++) {
      us4 pk;
#pragma unroll
      for (int v = 0; v < 4; v++) {
        float e = __expf(sf[n][v] - mn);
        psum += e;
        pk[v] = f2bf(e);
      }
      *(us4*)(psw + ((n * 32 + lg * 8) ^ psx)) = pk;   // P[q=lr][k=n*16+lg*4 ..+3]
    }
    psum += __shfl_xor(psum, 16);
    psum += __shfl_xor(psum, 32);
    l_run += psum;

    // rescale oacc rows q=lg*4+v with that q's alpha (broadcast from lane lr==q)
#pragma unroll
    for (int v = 0; v < 4; v++) {
      const float av = __shfl(alpha, lg * 4 + v);
#pragma unroll
      for (int dn = 0; dn < 4; dn++) oacc[dn][v] *= av;
    }

    // drain wave-local Ps writes before reading them (no block barrier needed)
    asm volatile("s_waitcnt lgkmcnt(0)" ::: "memory");
    __builtin_amdgcn_sched_barrier(0);

    // ---- PV: A = P[q=lr][k-frag], B = Vt[d=dn*16+lr][k-frag]; K=128 -> kc2=0..3 ----
#pragma unroll
    for (int kc2 = 0; kc2 < 4; kc2++) {
      short8 pf = *(const short8*)((const char*)&Ps[w][0] + lr * 256 +
                                   (((kc2 * 32 + lg * 8) * 2) ^ ((lr & 7) << 4)));
#pragma unroll
      for (int dn = 0; dn < 4; dn++) {
        const int row = dn * 16 + lr;
        short8 vf = *(const short8*)((const char*)Vt + row * 256 +
                                     (((kc2 * 32 + lg * 8) * 2) ^ ((row & 7) << 4)));
        oacc[dn] = __builtin_amdgcn_mfma_f32_16x16x32_bf16(pf, vf, oacc[dn], 0, 0, 0);
      }
    }
    __builtin_amdgcn_sched_barrier(0);
    __builtin_amdgcn_s_barrier();   // all waves done reading Ks/Vt before next overwrite
#pragma unroll
    for (int j = 0; j < 4; j++) { ck[j] = nkk[j]; cv[j] = nvv[j]; }
  }

  unsigned short* ob = o + (size_t)(b * SEQ + qt * 64 + w * 16) * DIMC + h * HDIM;
#pragma unroll
  for (int v = 0; v < 4; v++) {
    const float lv = __shfl(l_run, lg * 4 + v);
    const float inv = 1.0f / lv;
#pragma unroll
    for (int dn = 0; dn < 4; dn++)
      ob[(size_t)(lg * 4 + v) * DIMC + dn * 16 + lr] = f2bf(oacc[dn][v] * inv);
  }
}

extern "C" void kernel_launch(void* const* d_in, const int* in_sizes, int n_in,
                              void* d_out, int out_size, void* d_ws, size_t ws_size,
                              hipStream_t stream) {
  const float* x      = (const float*)d_in[0];
  const float* ln1_g  = (const float*)d_in[1];
  const float* ln1_b  = (const float*)d_in[2];
  const float* w_qkv  = (const float*)d_in[3];
  const float* b_qkv  = (const float*)d_in[4];
  const float* w_proj = (const float*)d_in[5];
  const float* b_proj = (const float*)d_in[6];
  const float* ln2_g  = (const float*)d_in[7];
  const float* ln2_b  = (const float*)d_in[8];
  const float* w_fc1  = (const float*)d_in[9];
  const float* b_fc1  = (const float*)d_in[10];
  const float* w_fc2  = (const float*)d_in[11];
  const float* b_fc2  = (const float*)d_in[12];
  float* out = (float*)d_out;

  char* p = (char*)d_ws;
  unsigned short* wqkvT  = (unsigned short*)p; p += (size_t)2304 * 768 * 2;
  unsigned short* wprojT = (unsigned short*)p; p += (size_t)768 * 768 * 2;
  unsigned short* wfc1T  = (unsigned short*)p; p += (size_t)3072 * 768 * 2;
  unsigned short* wfc2T  = (unsigned short*)p; p += (size_t)768 * 3072 * 2;
  unsigned short* h1     = (unsigned short*)p; p += (size_t)NTOK * 768 * 2;
  float*          x1     = (float*)p;          p += (size_t)NTOK * 768 * 4;
  unsigned short* qkv    = (unsigned short*)p; p += (size_t)NTOK * 2304 * 2;
  unsigned short* ob     = (unsigned short*)p; p += (size_t)NTOK * 768 * 2;
  unsigned short* g      = qkv;            // alias: qkv region, dead by FC1
  unsigned short* vT     = (unsigned short*)x1;  // alias: x1 dead until proj GEMM; vT dead after attn

  dim3 tb(32, 8);
  wtrans<<<dim3(2304 / 32, 768 / 32), tb, 0, stream>>>(w_qkv, wqkvT, 768, 2304);
  wtrans<<<dim3(768 / 32, 768 / 32), tb, 0, stream>>>(w_proj, wprojT, 768, 768);
  wtrans<<<dim3(3072 / 32, 768 / 32), tb, 0, stream>>>(w_fc1, wfc1T, 768, 3072);
  wtrans<<<dim3(768 / 32, 3072 / 32), tb, 0, stream>>>(w_fc2, wfc2T, 3072, 768);

  ln_768<<<NTOK, 256, 0, stream>>>(x, ln1_g, ln1_b, h1);
  gemm_bt<128, 0, 0, 1><<<dim3(18, 64), 256, 0, stream>>>(h1, wqkvT, b_qkv, nullptr, nullptr,
                                                          qkv, NTOK, 2304, 768);
  vtrans<<<dim3(24, 32, 8), tb, 0, stream>>>(qkv, vT);
  attn<<<dim3(16, 12, 8), 256, 0, stream>>>(qkv, vT, ob);
  gemm_bt64<0, 1, 0><<<dim3(6, 128), 256, 0, stream>>>(ob, wprojT, b_proj, x, x1, nullptr,
                                                       NTOK, 768, 768);
  ln_768<<<NTOK, 256, 0, stream>>>(x1, ln2_g, ln2_b, h1);
  gemm_bt<128, 1, 0, 1><<<dim3(24, 64), 256, 0, stream>>>(h1, wfc1T, b_fc1, nullptr, nullptr,
                                                          g, NTOK, 3072, 768);
  gemm_bt64<0, 1, 0><<<dim3(6, 128), 256, 0, stream>>>(g, wfc2T, b_fc2, x1, out, nullptr,
                                                       NTOK, 768, 3072);
}

// Round 12
// 271.958 us; speedup vs baseline: 1.4524x; 1.0670x over previous
//
#include <hip/hip_runtime.h>
#include <hip/hip_bf16.h>

typedef __attribute__((ext_vector_type(8))) short short8;
typedef __attribute__((ext_vector_type(4))) float f32x4;
typedef __attribute__((ext_vector_type(4))) unsigned short us4;

#define DIMC 768
#define HIDDENC 3072
#define NTOK 8192
#define SEQ 1024
#define NHEAD 12
#define HDIM 64

__device__ inline unsigned short f2bf(float f) {
  union { float f; unsigned u; } x; x.f = f;
  unsigned r = (x.u + 0x7FFFu + ((x.u >> 16) & 1u)) >> 16;
  return (unsigned short)r;
}

__device__ inline void gload_lds16(const void* g, void* lds) {
  __builtin_amdgcn_global_load_lds((const __attribute__((address_space(1))) unsigned*)g,
                                   (__attribute__((address_space(3))) unsigned*)lds, 16, 0, 0);
}

__device__ inline float gelu_fast(float u) {
  // gelu(u) ~= u * sigmoid(1.595769f*(u + 0.044715f*u^3)); inf-safe.
  const float c2u = u * (1.5957691216f + 0.0713548162f * u * u);
  return u - u * __builtin_amdgcn_rcpf(__expf(c2u) + 1.0f);
}

// ---------------- weight transpose + fp32->bf16 ----------------
// W: [K][N] f32  ->  Wt: [N][K] bf16
__global__ void wtrans(const float* __restrict__ W, unsigned short* __restrict__ Wt,
                       int K, int N) {
  __shared__ float tile[32][33];
  const int bx = blockIdx.x * 32;  // N
  const int by = blockIdx.y * 32;  // K
  const int tx = threadIdx.x, ty = threadIdx.y;
#pragma unroll
  for (int i = 0; i < 32; i += 8) tile[ty + i][tx] = W[(size_t)(by + ty + i) * N + bx + tx];
  __syncthreads();
#pragma unroll
  for (int i = 0; i < 32; i += 8)
    Wt[(size_t)(bx + ty + i) * K + by + tx] = f2bf(tile[tx][ty + i]);
}

// ---------------- V transpose: qkv V-part -> vT[b*768 + (h*64+d)][n] ----------------
__global__ void vtrans(const unsigned short* __restrict__ qkv, unsigned short* __restrict__ vT) {
  __shared__ unsigned short tile[32][33];
  const int bc = blockIdx.x * 32;  // c in [0,768)
  const int bn = blockIdx.y * 32;  // n in [0,1024)
  const int b = blockIdx.z;
  const int tx = threadIdx.x, ty = threadIdx.y;
#pragma unroll
  for (int i = 0; i < 32; i += 8)
    tile[ty + i][tx] = qkv[(size_t)(b * SEQ + bn + ty + i) * (3 * DIMC) + 2 * DIMC + bc + tx];
  __syncthreads();
#pragma unroll
  for (int i = 0; i < 32; i += 8)
    vT[(size_t)(b * DIMC + bc + ty + i) * SEQ + bn + tx] = tile[tx][ty + i];
}

// ---------------- LayerNorm over 768, f32 in -> bf16 out ----------------
__global__ __launch_bounds__(256) void ln_768(const float* __restrict__ x,
                                              const float* __restrict__ g,
                                              const float* __restrict__ b,
                                              unsigned short* __restrict__ out) {
  const int row = blockIdx.x;
  const int t = threadIdx.x;
  const float* xr = x + (size_t)row * DIMC;
  float v0 = xr[t], v1 = xr[t + 256], v2 = xr[t + 512];
  float s = v0 + v1 + v2;
  float ss = v0 * v0 + v1 * v1 + v2 * v2;
#pragma unroll
  for (int m = 1; m < 64; m <<= 1) { s += __shfl_xor(s, m); ss += __shfl_xor(ss, m); }
  __shared__ float red[8];
  const int w = t >> 6, l = t & 63;
  if (l == 0) { red[w] = s; red[4 + w] = ss; }
  __syncthreads();
  s = red[0] + red[1] + red[2] + red[3];
  ss = red[4] + red[5] + red[6] + red[7];
  const float mu = s * (1.0f / 768.0f);
  const float var = ss * (1.0f / 768.0f) - mu * mu;
  const float rstd = rsqrtf(var + 1e-5f);
  out[(size_t)row * DIMC + t]       = f2bf((v0 - mu) * rstd * g[t]       + b[t]);
  out[(size_t)row * DIMC + t + 256] = f2bf((v1 - mu) * rstd * g[t + 256] + b[t + 256]);
  out[(size_t)row * DIMC + t + 512] = f2bf((v2 - mu) * rstd * g[t + 512] + b[t + 512]);
}

// ---------------- GEMM v6 (BM=128, BN=128, BK=32): 3-stage pipeline, counted vmcnt ----
// T4: the main loop never drains vmcnt to 0 — vmcnt(4) waits only the OLDEST tile's 4
// global_load_lds; the newer stage stays in flight across the raw s_barrier. Per-wave
// vmcnt + immediate block barrier => all waves' oldest-tile loads have landed.
// XOR-slot LDS map (round-9 verified: coalesced staging, conflict-free reads).
template <int BN, int GELU, int RES, int OUT_BF16>
__global__ __launch_bounds__(256) void gemm_bt(const unsigned short* __restrict__ A,
                                               const unsigned short* __restrict__ Bt,
                                               const float* __restrict__ bias,
                                               const float* __restrict__ res,
                                               float* __restrict__ Cf,
                                               unsigned short* __restrict__ Cb,
                                               int M, int N, int K) {
  constexpr int NJ = BN / 32;
  __shared__ __align__(16) unsigned short As[3][128 * 32];
  __shared__ __align__(16) unsigned short Bs[3][BN * 32];
  const int gx = gridDim.x;
  const int nwg = gx * gridDim.y;
  const int orig = blockIdx.y * gx + blockIdx.x;
  const int cpx = nwg >> 3;                       // nwg % 8 == 0
  const int wg = (orig & 7) * cpx + (orig >> 3);
  const int bxx = wg % gx, byy = wg / gx;
  const int t = threadIdx.x;
  const int w = t >> 6, l = t & 63;
  const int lr = l & 15, lg = l >> 4;
  const int wr = w >> 1, wc = w & 1;
  const unsigned short* Ag = A + (size_t)byy * 128 * K;
  const unsigned short* Bg = Bt + (size_t)bxx * BN * K;
  const int kc1 = (t & 3) ^ ((t >> 3) & 3);
  const size_t a1 = (size_t)(t >> 2) * K + (size_t)kc1 * 8;
  const size_t a2 = a1 + (size_t)64 * K;
  const int fx = (lg ^ ((lr >> 1) & 3)) * 16;
  f32x4 acc[4][NJ] = {};

  auto stage = [&](int buf, int k0) {
    gload_lds16(Ag + a1 + k0, &As[buf][w * 512]);
    gload_lds16(Ag + a2 + k0, &As[buf][2048 + w * 512]);
    gload_lds16(Bg + a1 + k0, &Bs[buf][w * 512]);
    if (BN == 128) gload_lds16(Bg + a2 + k0, &Bs[buf][2048 + w * 512]);
  };
  auto compute = [&](int buf) {
    short8 af[4], bf[NJ];
#pragma unroll
    for (int i = 0; i < 4; i++)
      af[i] = *(const short8*)((const char*)&As[buf][0] +
                               (size_t)(wr * 64 + i * 16 + lr) * 64 + fx);
#pragma unroll
    for (int j = 0; j < NJ; j++)
      bf[j] = *(const short8*)((const char*)&Bs[buf][0] +
                               (size_t)(wc * (16 * NJ) + j * 16 + lr) * 64 + fx);
#pragma unroll
    for (int i = 0; i < 4; i++)
#pragma unroll
      for (int j = 0; j < NJ; j++)
        acc[i][j] = __builtin_amdgcn_mfma_f32_16x16x32_bf16(af[i], bf[j], acc[i][j], 0, 0, 0);
  };

  const int nt = K >> 5;   // 24 (QKV) / 96 (FC1); nt >= 2
  stage(0, 0);
  stage(1, 32);
  for (int tt = 0; tt < nt - 1; ++tt) {
    // wait for the OLDEST stage's loads only (4 newer stay in flight)
    if (BN == 128) asm volatile("s_waitcnt vmcnt(4)" ::: "memory");
    else           asm volatile("s_waitcnt vmcnt(3)" ::: "memory");
    __builtin_amdgcn_s_barrier();
    __builtin_amdgcn_sched_barrier(0);
    if (tt + 2 < nt) stage((tt + 2) % 3, (tt + 2) << 5);
    compute(tt % 3);
    __builtin_amdgcn_sched_barrier(0);
    __builtin_amdgcn_s_barrier();   // all waves done reading buf tt%3 before it's re-staged
  }
  asm volatile("s_waitcnt vmcnt(0)" ::: "memory");
  __builtin_amdgcn_s_barrier();
  compute((nt - 1) % 3);

  const int rbase = byy * 128 + wr * 64;
  const int cbase = bxx * BN + wc * (16 * NJ);
#pragma unroll
  for (int i = 0; i < 4; i++)
#pragma unroll
    for (int j = 0; j < NJ; j++) {
      const int c = cbase + j * 16 + lr;
      const float bz = bias[c];
#pragma unroll
      for (int v = 0; v < 4; v++) {
        const int r = rbase + i * 16 + lg * 4 + v;
        float val = acc[i][j][v] + bz;
        if (RES) val += res[(size_t)r * N + c];
        if (GELU) val = gelu_fast(val);
        if (OUT_BF16) Cb[(size_t)r * N + c] = f2bf(val);
        else          Cf[(size_t)r * N + c] = val;
      }
    }
}

// ---------------- GEMM v5 (BM=64, BN=128, BK=64): small-N shape for proj/FC2 ----------------
template <int GELU, int RES, int OUT_BF16>
__global__ __launch_bounds__(256) void gemm_bt64(const unsigned short* __restrict__ A,
                                                 const unsigned short* __restrict__ Bt,
                                                 const float* __restrict__ bias,
                                                 const float* __restrict__ res,
                                                 float* __restrict__ Cf,
                                                 unsigned short* __restrict__ Cb,
                                                 int M, int N, int K) {
  __shared__ __align__(16) unsigned short As[2][64 * 64];
  __shared__ __align__(16) unsigned short Bs[2][128 * 64];
  const int gx = gridDim.x;
  const int nwg = gx * gridDim.y;
  const int orig = blockIdx.y * gx + blockIdx.x;
  const int cpx = nwg >> 3;                       // nwg % 8 == 0
  const int wg = (orig & 7) * cpx + (orig >> 3);
  const int bxx = wg % gx, byy = wg / gx;
  const int t = threadIdx.x;
  const int w = t >> 6, l = t & 63;
  const int lr = l & 15, lg = l >> 4;
  const unsigned short* Ag = A + (size_t)byy * 64 * K;
  const unsigned short* Bg = Bt + (size_t)bxx * 128 * K;
  const int srow = t >> 3;
  const int sulog = (t & 7) ^ (srow & 7);
  const size_t sa = (size_t)srow * K + (size_t)sulog * 8;
  f32x4 acc[4][2] = {};

  auto stage = [&](int buf, int k0) {
    gload_lds16(Ag + sa + k0, &As[buf][w * 512]);
    gload_lds16(Ag + sa + (size_t)32 * K + k0, &As[buf][2048 + w * 512]);
    gload_lds16(Bg + sa + k0, &Bs[buf][w * 512]);
    gload_lds16(Bg + sa + (size_t)32 * K + k0, &Bs[buf][2048 + w * 512]);
    gload_lds16(Bg + sa + (size_t)64 * K + k0, &Bs[buf][4096 + w * 512]);
    gload_lds16(Bg + sa + (size_t)96 * K + k0, &Bs[buf][6144 + w * 512]);
  };
  auto compute = [&](int buf) {
#pragma unroll
    for (int kc = 0; kc < 2; kc++) {
      const int ux = ((kc * 4 + lg) ^ (lr & 7)) * 16;
      short8 af[4], bf[2];
#pragma unroll
      for (int i = 0; i < 4; i++)
        af[i] = *(const short8*)((const char*)&As[buf][0] + (size_t)(i * 16 + lr) * 128 + ux);
#pragma unroll
      for (int j = 0; j < 2; j++)
        bf[j] = *(const short8*)((const char*)&Bs[buf][0] +
                                 (size_t)((w * 2 + j) * 16 + lr) * 128 + ux);
#pragma unroll
      for (int i = 0; i < 4; i++)
#pragma unroll
        for (int j = 0; j < 2; j++)
          acc[i][j] = __builtin_amdgcn_mfma_f32_16x16x32_bf16(af[i], bf[j], acc[i][j], 0, 0, 0);
    }
  };

  const int nt = K >> 6;
  stage(0, 0);
  __syncthreads();
  for (int tt = 0; tt < nt; tt += 2) {
    stage(1, (tt + 1) << 6);
    compute(0);
    __syncthreads();
    if (tt + 2 < nt) stage(0, (tt + 2) << 6);
    compute(1);
    __syncthreads();
  }

  const int rbase = byy * 64;
  const int cbase = bxx * 128 + w * 32;
#pragma unroll
  for (int i = 0; i < 4; i++)
#pragma unroll
    for (int j = 0; j < 2; j++) {
      const int c = cbase + j * 16 + lr;
      const float bz = bias[c];
#pragma unroll
      for (int v = 0; v < 4; v++) {
        const int r = rbase + i * 16 + lg * 4 + v;
        float val = acc[i][j][v] + bz;
        if (RES) val += res[(size_t)r * N + c];
        if (GELU) val = gelu_fast(val);
        if (OUT_BF16) Cb[(size_t)r * N + c] = f2bf(val);
        else          Cf[(size_t)r * N + c] = val;
      }
    }
}

// ---------------- fused attention (v6: KVBLK=128) ----------------
__global__ __launch_bounds__(256) void attn(const unsigned short* __restrict__ qkv,
                                            const unsigned short* __restrict__ vT,
                                            unsigned short* __restrict__ o) {
  const int qt = blockIdx.x, h = blockIdx.y, b = blockIdx.z;
  const int t = threadIdx.x, w = t >> 6, l = t & 63;
  const int lr = l & 15, lg = l >> 4;
  const int ld = 3 * DIMC;
  __shared__ __align__(16) unsigned short Ks[128 * 64];
  __shared__ __align__(16) unsigned short Vt[64 * 128];
  __shared__ __align__(16) unsigned short Ps[4][16 * 128];

  const unsigned short* qb = qkv + (size_t)(b * SEQ + qt * 64 + w * 16) * ld + h * HDIM;
  short8 qf0 = *(const short8*)(qb + (size_t)lr * ld + lg * 8);
  short8 qf1 = *(const short8*)(qb + (size_t)lr * ld + 32 + lg * 8);

  const int rk = t >> 1, seg = t & 1;
  const unsigned short* kb_base = qkv + (size_t)(b * SEQ + rk) * ld + DIMC + h * HDIM + seg * 32;
  const int dv = t >> 2, seg4 = t & 3;
  const unsigned short* vrow = vT + (size_t)(b * DIMC + h * HDIM + dv) * SEQ + seg4 * 32;

  short8 ck[4], cv[4];
#pragma unroll
  for (int j = 0; j < 4; j++) ck[j] = *(const short8*)(kb_base + j * 8);
#pragma unroll
  for (int j = 0; j < 4; j++) cv[j] = *(const short8*)(vrow + j * 8);

  float m_run = -1e30f, l_run = 0.f;
  f32x4 oacc[4];
#pragma unroll
  for (int i = 0; i < 4; i++) oacc[i] = (f32x4){0.f, 0.f, 0.f, 0.f};

  for (int kt = 0; kt < 8; ++kt) {
    {
      char* ksb = (char*)Ks + rk * 128;
      const int swk = (rk & 7) << 4;
#pragma unroll
      for (int j = 0; j < 4; j++)
        *(short8*)(ksb + ((seg * 64 + j * 16) ^ swk)) = ck[j];
      char* vsb = (char*)Vt + dv * 256;
      const int swv = (dv & 7) << 4;
#pragma unroll
      for (int j = 0; j < 4; j++)
        *(short8*)(vsb + ((seg4 * 64 + j * 16) ^ swv)) = cv[j];
    }
    const int nk = (kt + 1) & 7;
    short8 nkk[4], nvv[4];
#pragma unroll
    for (int j = 0; j < 4; j++)
      nkk[j] = *(const short8*)(kb_base + (size_t)nk * 128 * ld + j * 8);
#pragma unroll
    for (int j = 0; j < 4; j++)
      nvv[j] = *(const short8*)(vrow + nk * 128 + j * 8);

    asm volatile("s_waitcnt lgkmcnt(0)" ::: "memory");
    __builtin_amdgcn_s_barrier();
    __builtin_amdgcn_sched_barrier(0);

    f32x4 sf[8];
#pragma unroll
    for (int n = 0; n < 8; n++) sf[n] = (f32x4){0.f, 0.f, 0.f, 0.f};
#pragma unroll
    for (int kc = 0; kc < 2; kc++) {
      short8 q = kc ? qf1 : qf0;
#pragma unroll
      for (int n = 0; n < 8; n++) {
        const int row = n * 16 + lr;
        short8 kf = *(const short8*)((const char*)Ks + row * 128 +
                                     (((kc * 32 + lg * 8) * 2) ^ ((row & 7) << 4)));
        sf[n] = __builtin_amdgcn_mfma_f32_16x16x32_bf16(kf, q, sf[n], 0, 0, 0);
      }
    }

    float tmax = -1e30f;
#pragma unroll
    for (int n = 0; n < 8; n++)
#pragma unroll
      for (int v = 0; v < 4; v++) {
        float s = sf[n][v] * 0.125f;
        s = fminf(fmaxf(s, -50.f), 50.f);
        sf[n][v] = s;
        tmax = fmaxf(tmax, s);
      }
    tmax = fmaxf(tmax, __shfl_xor(tmax, 16));
    tmax = fmaxf(tmax, __shfl_xor(tmax, 32));
    const float mn = fmaxf(m_run, tmax);
    const float alpha = __expf(m_run - mn);
    m_run = mn;
    l_run *= alpha;
    float psum = 0.f;
    char* psw = (char*)&Ps[w][0] + lr * 256;
    const int psx = (lr & 7) << 4;
#pragma unroll
    for (int n = 0; n < 8; n++) {
      us4 pk;
#pragma unroll
      for (int v = 0; v < 4; v++) {
        float e = __expf(sf[n][v] - mn);
        psum += e;
        pk[v] = f2bf(e);
      }
      *(us4*)(psw + ((n * 32 + lg * 8) ^ psx)) = pk;
    }
    psum += __shfl_xor(psum, 16);
    psum += __shfl_xor(psum, 32);
    l_run += psum;

#pragma unroll
    for (int v = 0; v < 4; v++) {
      const float av = __shfl(alpha, lg * 4 + v);
#pragma unroll
      for (int dn = 0; dn < 4; dn++) oacc[dn][v] *= av;
    }

    asm volatile("s_waitcnt lgkmcnt(0)" ::: "memory");
    __builtin_amdgcn_sched_barrier(0);

#pragma unroll
    for (int kc2 = 0; kc2 < 4; kc2++) {
      short8 pf = *(const short8*)((const char*)&Ps[w][0] + lr * 256 +
                                   (((kc2 * 32 + lg * 8) * 2) ^ ((lr & 7) << 4)));
#pragma unroll
      for (int dn = 0; dn < 4; dn++) {
        const int row = dn * 16 + lr;
        short8 vf = *(const short8*)((const char*)Vt + row * 256 +
                                     (((kc2 * 32 + lg * 8) * 2) ^ ((row & 7) << 4)));
        oacc[dn] = __builtin_amdgcn_mfma_f32_16x16x32_bf16(pf, vf, oacc[dn], 0, 0, 0);
      }
    }
    __builtin_amdgcn_sched_barrier(0);
    __builtin_amdgcn_s_barrier();
#pragma unroll
    for (int j = 0; j < 4; j++) { ck[j] = nkk[j]; cv[j] = nvv[j]; }
  }

  unsigned short* ob = o + (size_t)(b * SEQ + qt * 64 + w * 16) * DIMC + h * HDIM;
#pragma unroll
  for (int v = 0; v < 4; v++) {
    const float lv = __shfl(l_run, lg * 4 + v);
    const float inv = 1.0f / lv;
#pragma unroll
    for (int dn = 0; dn < 4; dn++)
      ob[(size_t)(lg * 4 + v) * DIMC + dn * 16 + lr] = f2bf(oacc[dn][v] * inv);
  }
}

extern "C" void kernel_launch(void* const* d_in, const int* in_sizes, int n_in,
                              void* d_out, int out_size, void* d_ws, size_t ws_size,
                              hipStream_t stream) {
  const float* x      = (const float*)d_in[0];
  const float* ln1_g  = (const float*)d_in[1];
  const float* ln1_b  = (const float*)d_in[2];
  const float* w_qkv  = (const float*)d_in[3];
  const float* b_qkv  = (const float*)d_in[4];
  const float* w_proj = (const float*)d_in[5];
  const float* b_proj = (const float*)d_in[6];
  const float* ln2_g  = (const float*)d_in[7];
  const float* ln2_b  = (const float*)d_in[8];
  const float* w_fc1  = (const float*)d_in[9];
  const float* b_fc1  = (const float*)d_in[10];
  const float* w_fc2  = (const float*)d_in[11];
  const float* b_fc2  = (const float*)d_in[12];
  float* out = (float*)d_out;

  char* p = (char*)d_ws;
  unsigned short* wqkvT  = (unsigned short*)p; p += (size_t)2304 * 768 * 2;
  unsigned short* wprojT = (unsigned short*)p; p += (size_t)768 * 768 * 2;
  unsigned short* wfc1T  = (unsigned short*)p; p += (size_t)3072 * 768 * 2;
  unsigned short* wfc2T  = (unsigned short*)p; p += (size_t)768 * 3072 * 2;
  unsigned short* h1     = (unsigned short*)p; p += (size_t)NTOK * 768 * 2;
  float*          x1     = (float*)p;          p += (size_t)NTOK * 768 * 4;
  unsigned short* qkv    = (unsigned short*)p; p += (size_t)NTOK * 2304 * 2;
  unsigned short* ob     = (unsigned short*)p; p += (size_t)NTOK * 768 * 2;
  unsigned short* g      = qkv;            // alias: qkv region, dead by FC1
  unsigned short* vT     = (unsigned short*)x1;  // alias: x1 dead until proj GEMM; vT dead after attn

  dim3 tb(32, 8);
  wtrans<<<dim3(2304 / 32, 768 / 32), tb, 0, stream>>>(w_qkv, wqkvT, 768, 2304);
  wtrans<<<dim3(768 / 32, 768 / 32), tb, 0, stream>>>(w_proj, wprojT, 768, 768);
  wtrans<<<dim3(3072 / 32, 768 / 32), tb, 0, stream>>>(w_fc1, wfc1T, 768, 3072);
  wtrans<<<dim3(768 / 32, 3072 / 32), tb, 0, stream>>>(w_fc2, wfc2T, 3072, 768);

  ln_768<<<NTOK, 256, 0, stream>>>(x, ln1_g, ln1_b, h1);
  gemm_bt<128, 0, 0, 1><<<dim3(18, 64), 256, 0, stream>>>(h1, wqkvT, b_qkv, nullptr, nullptr,
                                                          qkv, NTOK, 2304, 768);
  vtrans<<<dim3(24, 32, 8), tb, 0, stream>>>(qkv, vT);
  attn<<<dim3(16, 12, 8), 256, 0, stream>>>(qkv, vT, ob);
  gemm_bt64<0, 1, 0><<<dim3(6, 128), 256, 0, stream>>>(ob, wprojT, b_proj, x, x1, nullptr,
                                                       NTOK, 768, 768);
  ln_768<<<NTOK, 256, 0, stream>>>(x1, ln2_g, ln2_b, h1);
  gemm_bt<128, 1, 0, 1><<<dim3(24, 64), 256, 0, stream>>>(h1, wfc1T, b_fc1, nullptr, nullptr,
                                                          g, NTOK, 3072, 768);
  gemm_bt64<0, 1, 0><<<dim3(6, 128), 256, 0, stream>>>(g, wfc2T, b_fc2, x1, out, nullptr,
                                                       NTOK, 768, 3072);
}

// Round 13
// 265.858 us; speedup vs baseline: 1.4857x; 1.0229x over previous
//
#include <hip/hip_runtime.h>
#include <hip/hip_bf16.h>

typedef __attribute__((ext_vector_type(8))) short short8;
typedef __attribute__((ext_vector_type(4))) float f32x4;
typedef __attribute__((ext_vector_type(4))) unsigned short us4;

#define DIMC 768
#define HIDDENC 3072
#define NTOK 8192
#define SEQ 1024
#define NHEAD 12
#define HDIM 64

__device__ inline unsigned short f2bf(float f) {
  union { float f; unsigned u; } x; x.f = f;
  unsigned r = (x.u + 0x7FFFu + ((x.u >> 16) & 1u)) >> 16;
  return (unsigned short)r;
}

__device__ inline void gload_lds16(const void* g, void* lds) {
  __builtin_amdgcn_global_load_lds((const __attribute__((address_space(1))) unsigned*)g,
                                   (__attribute__((address_space(3))) unsigned*)lds, 16, 0, 0);
}

__device__ inline float gelu_fast(float u) {
  // gelu(u) ~= u * sigmoid(1.595769f*(u + 0.044715f*u^3)); inf-safe.
  const float c2u = u * (1.5957691216f + 0.0713548162f * u * u);
  return u - u * __builtin_amdgcn_rcpf(__expf(c2u) + 1.0f);
}

// ---------------- weight transpose + fp32->bf16 ----------------
// W: [K][N] f32  ->  Wt: [N][K] bf16
__global__ void wtrans(const float* __restrict__ W, unsigned short* __restrict__ Wt,
                       int K, int N) {
  __shared__ float tile[32][33];
  const int bx = blockIdx.x * 32;  // N
  const int by = blockIdx.y * 32;  // K
  const int tx = threadIdx.x, ty = threadIdx.y;
#pragma unroll
  for (int i = 0; i < 32; i += 8) tile[ty + i][tx] = W[(size_t)(by + ty + i) * N + bx + tx];
  __syncthreads();
#pragma unroll
  for (int i = 0; i < 32; i += 8)
    Wt[(size_t)(bx + ty + i) * K + by + tx] = f2bf(tile[tx][ty + i]);
}

// ---------------- V transpose: qkv V-part -> vT[b*768 + (h*64+d)][n] ----------------
__global__ void vtrans(const unsigned short* __restrict__ qkv, unsigned short* __restrict__ vT) {
  __shared__ unsigned short tile[32][33];
  const int bc = blockIdx.x * 32;  // c in [0,768)
  const int bn = blockIdx.y * 32;  // n in [0,1024)
  const int b = blockIdx.z;
  const int tx = threadIdx.x, ty = threadIdx.y;
#pragma unroll
  for (int i = 0; i < 32; i += 8)
    tile[ty + i][tx] = qkv[(size_t)(b * SEQ + bn + ty + i) * (3 * DIMC) + 2 * DIMC + bc + tx];
  __syncthreads();
#pragma unroll
  for (int i = 0; i < 32; i += 8)
    vT[(size_t)(b * DIMC + bc + ty + i) * SEQ + bn + tx] = tile[tx][ty + i];
}

// ---------------- LayerNorm over 768, f32 in -> bf16 out ----------------
__global__ __launch_bounds__(256) void ln_768(const float* __restrict__ x,
                                              const float* __restrict__ g,
                                              const float* __restrict__ b,
                                              unsigned short* __restrict__ out) {
  const int row = blockIdx.x;
  const int t = threadIdx.x;
  const float* xr = x + (size_t)row * DIMC;
  float v0 = xr[t], v1 = xr[t + 256], v2 = xr[t + 512];
  float s = v0 + v1 + v2;
  float ss = v0 * v0 + v1 * v1 + v2 * v2;
#pragma unroll
  for (int m = 1; m < 64; m <<= 1) { s += __shfl_xor(s, m); ss += __shfl_xor(ss, m); }
  __shared__ float red[8];
  const int w = t >> 6, l = t & 63;
  if (l == 0) { red[w] = s; red[4 + w] = ss; }
  __syncthreads();
  s = red[0] + red[1] + red[2] + red[3];
  ss = red[4] + red[5] + red[6] + red[7];
  const float mu = s * (1.0f / 768.0f);
  const float var = ss * (1.0f / 768.0f) - mu * mu;
  const float rstd = rsqrtf(var + 1e-5f);
  out[(size_t)row * DIMC + t]       = f2bf((v0 - mu) * rstd * g[t]       + b[t]);
  out[(size_t)row * DIMC + t + 256] = f2bf((v1 - mu) * rstd * g[t + 256] + b[t + 256]);
  out[(size_t)row * DIMC + t + 512] = f2bf((v2 - mu) * rstd * g[t + 512] + b[t + 512]);
}

// ---------------- GEMM v6 (BM=128, BN=128, BK=32): 3-stage pipeline, counted vmcnt ----
// T4: main loop never drains vmcnt to 0 — vmcnt(4) waits only the OLDEST tile's loads.
// XOR-slot LDS map (coalesced staging, conflict-free reads). QSCALE: fold
// 0.125*log2e into Q columns (c<768) so attn softmax runs in exp2 domain.
template <int BN, int GELU, int RES, int OUT_BF16, int QSCALE>
__global__ __launch_bounds__(256) void gemm_bt(const unsigned short* __restrict__ A,
                                               const unsigned short* __restrict__ Bt,
                                               const float* __restrict__ bias,
                                               const float* __restrict__ res,
                                               float* __restrict__ Cf,
                                               unsigned short* __restrict__ Cb,
                                               int M, int N, int K) {
  constexpr int NJ = BN / 32;
  __shared__ __align__(16) unsigned short As[3][128 * 32];
  __shared__ __align__(16) unsigned short Bs[3][BN * 32];
  const int gx = gridDim.x;
  const int nwg = gx * gridDim.y;
  const int orig = blockIdx.y * gx + blockIdx.x;
  const int cpx = nwg >> 3;                       // nwg % 8 == 0
  const int wg = (orig & 7) * cpx + (orig >> 3);
  const int bxx = wg % gx, byy = wg / gx;
  const int t = threadIdx.x;
  const int w = t >> 6, l = t & 63;
  const int lr = l & 15, lg = l >> 4;
  const int wr = w >> 1, wc = w & 1;
  const unsigned short* Ag = A + (size_t)byy * 128 * K;
  const unsigned short* Bg = Bt + (size_t)bxx * BN * K;
  const int kc1 = (t & 3) ^ ((t >> 3) & 3);
  const size_t a1 = (size_t)(t >> 2) * K + (size_t)kc1 * 8;
  const size_t a2 = a1 + (size_t)64 * K;
  const int fx = (lg ^ ((lr >> 1) & 3)) * 16;
  f32x4 acc[4][NJ] = {};

  auto stage = [&](int buf, int k0) {
    gload_lds16(Ag + a1 + k0, &As[buf][w * 512]);
    gload_lds16(Ag + a2 + k0, &As[buf][2048 + w * 512]);
    gload_lds16(Bg + a1 + k0, &Bs[buf][w * 512]);
    if (BN == 128) gload_lds16(Bg + a2 + k0, &Bs[buf][2048 + w * 512]);
  };
  auto compute = [&](int buf) {
    short8 af[4], bf[NJ];
#pragma unroll
    for (int i = 0; i < 4; i++)
      af[i] = *(const short8*)((const char*)&As[buf][0] +
                               (size_t)(wr * 64 + i * 16 + lr) * 64 + fx);
#pragma unroll
    for (int j = 0; j < NJ; j++)
      bf[j] = *(const short8*)((const char*)&Bs[buf][0] +
                               (size_t)(wc * (16 * NJ) + j * 16 + lr) * 64 + fx);
#pragma unroll
    for (int i = 0; i < 4; i++)
#pragma unroll
      for (int j = 0; j < NJ; j++)
        acc[i][j] = __builtin_amdgcn_mfma_f32_16x16x32_bf16(af[i], bf[j], acc[i][j], 0, 0, 0);
  };

  const int nt = K >> 5;   // 24 (QKV) / 96 (FC1); nt >= 2
  stage(0, 0);
  stage(1, 32);
  for (int tt = 0; tt < nt - 1; ++tt) {
    if (BN == 128) asm volatile("s_waitcnt vmcnt(4)" ::: "memory");
    else           asm volatile("s_waitcnt vmcnt(3)" ::: "memory");
    __builtin_amdgcn_s_barrier();
    __builtin_amdgcn_sched_barrier(0);
    if (tt + 2 < nt) stage((tt + 2) % 3, (tt + 2) << 5);
    compute(tt % 3);
    __builtin_amdgcn_sched_barrier(0);
    __builtin_amdgcn_s_barrier();
  }
  asm volatile("s_waitcnt vmcnt(0)" ::: "memory");
  __builtin_amdgcn_s_barrier();
  compute((nt - 1) % 3);

  const int rbase = byy * 128 + wr * 64;
  const int cbase = bxx * BN + wc * (16 * NJ);
#pragma unroll
  for (int i = 0; i < 4; i++)
#pragma unroll
    for (int j = 0; j < NJ; j++) {
      const int c = cbase + j * 16 + lr;
      const float bz = bias[c];
#pragma unroll
      for (int v = 0; v < 4; v++) {
        const int r = rbase + i * 16 + lg * 4 + v;
        float val = acc[i][j][v] + bz;
        if (RES) val += res[(size_t)r * N + c];
        if (GELU) val = gelu_fast(val);
        if (QSCALE) { if (c < DIMC) val *= 0.18033688011112042f; }  // 0.125*log2(e)
        if (OUT_BF16) Cb[(size_t)r * N + c] = f2bf(val);
        else          Cf[(size_t)r * N + c] = val;
      }
    }
}

// ---------------- GEMM v5 (BM=64, BN=128, BK=64): small-N shape for proj/FC2 ----------------
template <int GELU, int RES, int OUT_BF16>
__global__ __launch_bounds__(256) void gemm_bt64(const unsigned short* __restrict__ A,
                                                 const unsigned short* __restrict__ Bt,
                                                 const float* __restrict__ bias,
                                                 const float* __restrict__ res,
                                                 float* __restrict__ Cf,
                                                 unsigned short* __restrict__ Cb,
                                                 int M, int N, int K) {
  __shared__ __align__(16) unsigned short As[2][64 * 64];
  __shared__ __align__(16) unsigned short Bs[2][128 * 64];
  const int gx = gridDim.x;
  const int nwg = gx * gridDim.y;
  const int orig = blockIdx.y * gx + blockIdx.x;
  const int cpx = nwg >> 3;                       // nwg % 8 == 0
  const int wg = (orig & 7) * cpx + (orig >> 3);
  const int bxx = wg % gx, byy = wg / gx;
  const int t = threadIdx.x;
  const int w = t >> 6, l = t & 63;
  const int lr = l & 15, lg = l >> 4;
  const unsigned short* Ag = A + (size_t)byy * 64 * K;
  const unsigned short* Bg = Bt + (size_t)bxx * 128 * K;
  const int srow = t >> 3;
  const int sulog = (t & 7) ^ (srow & 7);
  const size_t sa = (size_t)srow * K + (size_t)sulog * 8;
  f32x4 acc[4][2] = {};

  auto stage = [&](int buf, int k0) {
    gload_lds16(Ag + sa + k0, &As[buf][w * 512]);
    gload_lds16(Ag + sa + (size_t)32 * K + k0, &As[buf][2048 + w * 512]);
    gload_lds16(Bg + sa + k0, &Bs[buf][w * 512]);
    gload_lds16(Bg + sa + (size_t)32 * K + k0, &Bs[buf][2048 + w * 512]);
    gload_lds16(Bg + sa + (size_t)64 * K + k0, &Bs[buf][4096 + w * 512]);
    gload_lds16(Bg + sa + (size_t)96 * K + k0, &Bs[buf][6144 + w * 512]);
  };
  auto compute = [&](int buf) {
#pragma unroll
    for (int kc = 0; kc < 2; kc++) {
      const int ux = ((kc * 4 + lg) ^ (lr & 7)) * 16;
      short8 af[4], bf[2];
#pragma unroll
      for (int i = 0; i < 4; i++)
        af[i] = *(const short8*)((const char*)&As[buf][0] + (size_t)(i * 16 + lr) * 128 + ux);
#pragma unroll
      for (int j = 0; j < 2; j++)
        bf[j] = *(const short8*)((const char*)&Bs[buf][0] +
                                 (size_t)((w * 2 + j) * 16 + lr) * 128 + ux);
#pragma unroll
      for (int i = 0; i < 4; i++)
#pragma unroll
        for (int j = 0; j < 2; j++)
          acc[i][j] = __builtin_amdgcn_mfma_f32_16x16x32_bf16(af[i], bf[j], acc[i][j], 0, 0, 0);
    }
  };

  const int nt = K >> 6;
  stage(0, 0);
  __syncthreads();
  for (int tt = 0; tt < nt; tt += 2) {
    stage(1, (tt + 1) << 6);
    compute(0);
    __syncthreads();
    if (tt + 2 < nt) stage(0, (tt + 2) << 6);
    compute(1);
    __syncthreads();
  }

  const int rbase = byy * 64;
  const int cbase = bxx * 128 + w * 32;
#pragma unroll
  for (int i = 0; i < 4; i++)
#pragma unroll
    for (int j = 0; j < 2; j++) {
      const int c = cbase + j * 16 + lr;
      const float bz = bias[c];
#pragma unroll
      for (int v = 0; v < 4; v++) {
        const int r = rbase + i * 16 + lg * 4 + v;
        float val = acc[i][j][v] + bz;
        if (RES) val += res[(size_t)r * N + c];
        if (GELU) val = gelu_fast(val);
        if (OUT_BF16) Cb[(size_t)r * N + c] = f2bf(val);
        else          Cf[(size_t)r * N + c] = val;
      }
    }
}

// ---------------- fused attention (v7: KVBLK=128, exp2-domain softmax, cvt_pk) ----
// Q pre-scaled by 0.125*log2e in QKV epilogue => S is in log2 units.
// clamp at +-50*log2e; P = exp2(S - m); alpha = exp2(m_old - m_new).
__global__ __launch_bounds__(256) void attn(const unsigned short* __restrict__ qkv,
                                            const unsigned short* __restrict__ vT,
                                            unsigned short* __restrict__ o) {
  const int qt = blockIdx.x, h = blockIdx.y, b = blockIdx.z;
  const int t = threadIdx.x, w = t >> 6, l = t & 63;
  const int lr = l & 15, lg = l >> 4;
  const int ld = 3 * DIMC;
  __shared__ __align__(16) unsigned short Ks[128 * 64];
  __shared__ __align__(16) unsigned short Vt[64 * 128];
  __shared__ __align__(16) unsigned short Ps[4][16 * 128];

  const unsigned short* qb = qkv + (size_t)(b * SEQ + qt * 64 + w * 16) * ld + h * HDIM;
  short8 qf0 = *(const short8*)(qb + (size_t)lr * ld + lg * 8);
  short8 qf1 = *(const short8*)(qb + (size_t)lr * ld + 32 + lg * 8);

  const int rk = t >> 1, seg = t & 1;
  const unsigned short* kb_base = qkv + (size_t)(b * SEQ + rk) * ld + DIMC + h * HDIM + seg * 32;
  const int dv = t >> 2, seg4 = t & 3;
  const unsigned short* vrow = vT + (size_t)(b * DIMC + h * HDIM + dv) * SEQ + seg4 * 32;

  short8 ck[4], cv[4];
#pragma unroll
  for (int j = 0; j < 4; j++) ck[j] = *(const short8*)(kb_base + j * 8);
#pragma unroll
  for (int j = 0; j < 4; j++) cv[j] = *(const short8*)(vrow + j * 8);

  float m_run = -1e30f, l_run = 0.f;
  f32x4 oacc[4];
#pragma unroll
  for (int i = 0; i < 4; i++) oacc[i] = (f32x4){0.f, 0.f, 0.f, 0.f};

  for (int kt = 0; kt < 8; ++kt) {
    {
      char* ksb = (char*)Ks + rk * 128;
      const int swk = (rk & 7) << 4;
#pragma unroll
      for (int j = 0; j < 4; j++)
        *(short8*)(ksb + ((seg * 64 + j * 16) ^ swk)) = ck[j];
      char* vsb = (char*)Vt + dv * 256;
      const int swv = (dv & 7) << 4;
#pragma unroll
      for (int j = 0; j < 4; j++)
        *(short8*)(vsb + ((seg4 * 64 + j * 16) ^ swv)) = cv[j];
    }
    const int nk = (kt + 1) & 7;
    short8 nkk[4], nvv[4];
#pragma unroll
    for (int j = 0; j < 4; j++)
      nkk[j] = *(const short8*)(kb_base + (size_t)nk * 128 * ld + j * 8);
#pragma unroll
    for (int j = 0; j < 4; j++)
      nvv[j] = *(const short8*)(vrow + nk * 128 + j * 8);

    asm volatile("s_waitcnt lgkmcnt(0)" ::: "memory");
    __builtin_amdgcn_s_barrier();
    __builtin_amdgcn_sched_barrier(0);

    f32x4 sf[8];
#pragma unroll
    for (int n = 0; n < 8; n++) sf[n] = (f32x4){0.f, 0.f, 0.f, 0.f};
#pragma unroll
    for (int kc = 0; kc < 2; kc++) {
      short8 q = kc ? qf1 : qf0;
#pragma unroll
      for (int n = 0; n < 8; n++) {
        const int row = n * 16 + lr;
        short8 kf = *(const short8*)((const char*)Ks + row * 128 +
                                     (((kc * 32 + lg * 8) * 2) ^ ((row & 7) << 4)));
        sf[n] = __builtin_amdgcn_mfma_f32_16x16x32_bf16(kf, q, sf[n], 0, 0, 0);
      }
    }

    // ---- online softmax in exp2 domain; q = lr local ----
    float tmax = -1e30f;
#pragma unroll
    for (int n = 0; n < 8; n++)
#pragma unroll
      for (int v = 0; v < 4; v++) {
        float s = sf[n][v];
        s = fminf(fmaxf(s, -72.134752f), 72.134752f);   // +-50*log2(e)
        sf[n][v] = s;
        tmax = fmaxf(tmax, s);
      }
    tmax = fmaxf(tmax, __shfl_xor(tmax, 16));
    tmax = fmaxf(tmax, __shfl_xor(tmax, 32));
    const float mn = fmaxf(m_run, tmax);
    const float alpha = __builtin_amdgcn_exp2f(m_run - mn);
    m_run = mn;
    l_run *= alpha;
    float psum = 0.f;
    char* psw = (char*)&Ps[w][0] + lr * 256;
    const int psx = (lr & 7) << 4;
#pragma unroll
    for (int n = 0; n < 8; n++) {
      const float e0 = __builtin_amdgcn_exp2f(sf[n][0] - mn);
      const float e1 = __builtin_amdgcn_exp2f(sf[n][1] - mn);
      const float e2 = __builtin_amdgcn_exp2f(sf[n][2] - mn);
      const float e3 = __builtin_amdgcn_exp2f(sf[n][3] - mn);
      psum += (e0 + e1) + (e2 + e3);
      unsigned p01, p23;
      asm("v_cvt_pk_bf16_f32 %0, %1, %2" : "=v"(p01) : "v"(e0), "v"(e1));
      asm("v_cvt_pk_bf16_f32 %0, %1, %2" : "=v"(p23) : "v"(e2), "v"(e3));
      const unsigned long long pk = ((unsigned long long)p23 << 32) | p01;
      *(unsigned long long*)(psw + ((n * 32 + lg * 8) ^ psx)) = pk;
    }
    psum += __shfl_xor(psum, 16);
    psum += __shfl_xor(psum, 32);
    l_run += psum;

#pragma unroll
    for (int v = 0; v < 4; v++) {
      const float av = __shfl(alpha, lg * 4 + v);
#pragma unroll
      for (int dn = 0; dn < 4; dn++) oacc[dn][v] *= av;
    }

    asm volatile("s_waitcnt lgkmcnt(0)" ::: "memory");
    __builtin_amdgcn_sched_barrier(0);

#pragma unroll
    for (int kc2 = 0; kc2 < 4; kc2++) {
      short8 pf = *(const short8*)((const char*)&Ps[w][0] + lr * 256 +
                                   (((kc2 * 32 + lg * 8) * 2) ^ ((lr & 7) << 4)));
#pragma unroll
      for (int dn = 0; dn < 4; dn++) {
        const int row = dn * 16 + lr;
        short8 vf = *(const short8*)((const char*)Vt + row * 256 +
                                     (((kc2 * 32 + lg * 8) * 2) ^ ((row & 7) << 4)));
        oacc[dn] = __builtin_amdgcn_mfma_f32_16x16x32_bf16(pf, vf, oacc[dn], 0, 0, 0);
      }
    }
    __builtin_amdgcn_sched_barrier(0);
    __builtin_amdgcn_s_barrier();
#pragma unroll
    for (int j = 0; j < 4; j++) { ck[j] = nkk[j]; cv[j] = nvv[j]; }
  }

  unsigned short* ob = o + (size_t)(b * SEQ + qt * 64 + w * 16) * DIMC + h * HDIM;
#pragma unroll
  for (int v = 0; v < 4; v++) {
    const float lv = __shfl(l_run, lg * 4 + v);
    const float inv = 1.0f / lv;
#pragma unroll
    for (int dn = 0; dn < 4; dn++)
      ob[(size_t)(lg * 4 + v) * DIMC + dn * 16 + lr] = f2bf(oacc[dn][v] * inv);
  }
}

extern "C" void kernel_launch(void* const* d_in, const int* in_sizes, int n_in,
                              void* d_out, int out_size, void* d_ws, size_t ws_size,
                              hipStream_t stream) {
  const float* x      = (const float*)d_in[0];
  const float* ln1_g  = (const float*)d_in[1];
  const float* ln1_b  = (const float*)d_in[2];
  const float* w_qkv  = (const float*)d_in[3];
  const float* b_qkv  = (const float*)d_in[4];
  const float* w_proj = (const float*)d_in[5];
  const float* b_proj = (const float*)d_in[6];
  const float* ln2_g  = (const float*)d_in[7];
  const float* ln2_b  = (const float*)d_in[8];
  const float* w_fc1  = (const float*)d_in[9];
  const float* b_fc1  = (const float*)d_in[10];
  const float* w_fc2  = (const float*)d_in[11];
  const float* b_fc2  = (const float*)d_in[12];
  float* out = (float*)d_out;

  char* p = (char*)d_ws;
  unsigned short* wqkvT  = (unsigned short*)p; p += (size_t)2304 * 768 * 2;
  unsigned short* wprojT = (unsigned short*)p; p += (size_t)768 * 768 * 2;
  unsigned short* wfc1T  = (unsigned short*)p; p += (size_t)3072 * 768 * 2;
  unsigned short* wfc2T  = (unsigned short*)p; p += (size_t)768 * 3072 * 2;
  unsigned short* h1     = (unsigned short*)p; p += (size_t)NTOK * 768 * 2;
  float*          x1     = (float*)p;          p += (size_t)NTOK * 768 * 4;
  unsigned short* qkv    = (unsigned short*)p; p += (size_t)NTOK * 2304 * 2;
  unsigned short* ob     = (unsigned short*)p; p += (size_t)NTOK * 768 * 2;
  unsigned short* g      = qkv;            // alias: qkv region, dead by FC1
  unsigned short* vT     = (unsigned short*)x1;  // alias: x1 dead until proj GEMM; vT dead after attn

  dim3 tb(32, 8);
  wtrans<<<dim3(2304 / 32, 768 / 32), tb, 0, stream>>>(w_qkv, wqkvT, 768, 2304);
  wtrans<<<dim3(768 / 32, 768 / 32), tb, 0, stream>>>(w_proj, wprojT, 768, 768);
  wtrans<<<dim3(3072 / 32, 768 / 32), tb, 0, stream>>>(w_fc1, wfc1T, 768, 3072);
  wtrans<<<dim3(768 / 32, 3072 / 32), tb, 0, stream>>>(w_fc2, wfc2T, 3072, 768);

  ln_768<<<NTOK, 256, 0, stream>>>(x, ln1_g, ln1_b, h1);
  gemm_bt<128, 0, 0, 1, 1><<<dim3(18, 64), 256, 0, stream>>>(h1, wqkvT, b_qkv, nullptr, nullptr,
                                                             qkv, NTOK, 2304, 768);
  vtrans<<<dim3(24, 32, 8), tb, 0, stream>>>(qkv, vT);
  attn<<<dim3(16, 12, 8), 256, 0, stream>>>(qkv, vT, ob);
  gemm_bt64<0, 1, 0><<<dim3(6, 128), 256, 0, stream>>>(ob, wprojT, b_proj, x, x1, nullptr,
                                                       NTOK, 768, 768);
  ln_768<<<NTOK, 256, 0, stream>>>(x1, ln2_g, ln2_b, h1);
  gemm_bt<128, 1, 0, 1, 0><<<dim3(24, 64), 256, 0, stream>>>(h1, wfc1T, b_fc1, nullptr, nullptr,
                                                             g, NTOK, 3072, 768);
  gemm_bt64<0, 1, 0><<<dim3(6, 128), 256, 0, stream>>>(g, wfc2T, b_fc2, x1, out, nullptr,
                                                       NTOK, 768, 3072);
}